// Round 3
// baseline (632.676 us; speedup 1.0000x reference)
//
#include <hip/hip_runtime.h>

typedef unsigned short u16;
typedef unsigned int u32;

#define T_ 768
#define D_ 24
#define S_ 576
#define Q_ 32
#define K_ 128
#define CA_ 128
#define CP_ 16
#define CT_ 384
#define H_ 4
#define DH_ 32
#define SQ_ (S_*Q_)
#define SK_ (S_*K_)

__device__ __forceinline__ float b2f(u16 u){ return __uint_as_float(((u32)u)<<16); }
__device__ __forceinline__ u16 f2b(float f){ u32 x=__float_as_uint(f); return (u16)((x + 0x7fffu + ((x>>16)&1u))>>16); }

// ---- N1: per-atom conditioning gathered to query slots; also qrp/quid ----
__global__ __launch_bounds__(128) void n_qsc(
    const float* __restrict__ pos, const float* __restrict__ rmask, const float* __restrict__ charge,
    const float* __restrict__ amask, const int* __restrict__ elem, const int* __restrict__ chars,
    const int* __restrict__ uid, const int* __restrict__ t2q,
    const float* __restrict__ w_pos, const float* __restrict__ w_mask, const float* __restrict__ w_elem,
    const float* __restrict__ w_chg, const float* __restrict__ w_name,
    float* __restrict__ qsc, float* __restrict__ qmask, float* __restrict__ qrp, int* __restrict__ quid,
    float* __restrict__ out_qsc, float* __restrict__ out_qmask)
{
  int slot = blockIdx.x, ch = threadIdx.x;
  int a = t2q[slot];
  float p0 = pos[a*3+0], p1 = pos[a*3+1], p2 = pos[a*3+2];
  float m  = rmask[a];
  float cg = asinhf(charge[a]);
  int e  = elem[a];
  int c0 = chars[a*4+0], c1 = chars[a*4+1], c2 = chars[a*4+2], c3 = chars[a*4+3];
  float v = p0*w_pos[0*CA_+ch] + p1*w_pos[1*CA_+ch] + p2*w_pos[2*CA_+ch];
  v += m * w_mask[ch];
  v += w_elem[e*CA_+ch];
  v += cg * w_chg[ch];
  v += w_name[(0*64+c0)*CA_+ch] + w_name[(1*64+c1)*CA_+ch]
     + w_name[(2*64+c2)*CA_+ch] + w_name[(3*64+c3)*CA_+ch];
  v *= m;
  qsc[(size_t)slot*CA_+ch] = v;
  out_qsc[(size_t)slot*CA_+ch] = v;
  if (ch < 3) qrp[slot*3+ch] = pos[a*3+ch];
  if (ch == 0){
    float am = amask[a];
    qmask[slot] = am;
    out_qmask[slot] = am;
    quid[slot] = uid[a];
  }
}

// ---- N2: key-space gathers. 4 rows/block, one float4 per thread ----
__global__ __launch_bounds__(128) void n_keys(
    const float* __restrict__ qsc, const float* __restrict__ qmask, const float* __restrict__ qrp,
    const int* __restrict__ uid, const int* __restrict__ q2k,
    float* __restrict__ krp, int* __restrict__ kuid,
    float* __restrict__ out_ksc, float* __restrict__ out_kmask)
{
  int r = threadIdx.x >> 5;
  int e = threadIdx.x & 31;
  int sk = blockIdx.x*4 + r;
  int j = q2k[sk];
  *(float4*)&out_ksc[(size_t)sk*CA_ + e*4] = *(const float4*)&qsc[(size_t)j*CA_ + e*4];
  if (e < 3) krp[sk*3+e] = qrp[j*3+e];
  if (e == 0){
    out_kmask[sk] = qmask[j];
    kuid[sk] = uid[j];
  }
}

// ---- N3: fused QKV projection. Block = 16 rows, 128 threads (thread = out col).
//      X read via wave-uniform addresses -> scalar loads (SGPR), no LDS.
//      Single X sweep feeds Q,K,V accumulators (48 regs). ----
__global__ __launch_bounds__(128) void n_qkv(
    const float* __restrict__ X, const float* __restrict__ wq, const float* __restrict__ wk,
    const float* __restrict__ wv, float* __restrict__ Qp, float* __restrict__ Kp, float* __restrict__ Vp)
{
  int c = threadIdx.x;
  size_t r0 = (size_t)blockIdx.x * 16;
  float aq[16], ak[16], av[16];
  #pragma unroll
  for (int r = 0; r < 16; ++r){ aq[r] = 0.f; ak[r] = 0.f; av[r] = 0.f; }
  #pragma unroll 4
  for (int i = 0; i < CA_; ++i){
    float q = wq[i*CA_+c];
    float k = wk[i*CA_+c];
    float v = wv[i*CA_+c];
    #pragma unroll
    for (int r = 0; r < 16; ++r){
      float x = X[(r0+r)*CA_ + i];     // uniform -> s_load
      aq[r] += x * q;
      ak[r] += x * k;
      av[r] += x * v;
    }
  }
  #pragma unroll
  for (int r = 0; r < 16; ++r){
    Qp[(r0+r)*CA_+c] = aq[r] * 0.17677669529663687f;
    Kp[(r0+r)*CA_+c] = ak[r];
    Vp[(r0+r)*CA_+c] = av[r];
  }
}

// ---- N4: fused row+col 128->16 relu-linear. Block = 4 rows x 32 cols (16 row, 16 col) ----
__global__ __launch_bounds__(128) void n_proj16b(
    const float* __restrict__ X, const float* __restrict__ Wr, const float* __restrict__ Wc,
    float* __restrict__ Yr, float* __restrict__ Yc)
{
  int row = blockIdx.x*4 + (threadIdx.x >> 5);
  int c = threadIdx.x & 31;
  const float* W = (c < 16) ? Wr : Wc;
  float* Y = (c < 16) ? Yr : Yc;
  int cc = c & 15;
  float acc = 0.f;
  for (int i = 0; i < CA_; ++i)
    acc += fmaxf(X[(size_t)row*CA_+i], 0.f) * W[i*CP_+cc];
  Y[(size_t)row*CP_+cc] = acc;
}

// ---- N5: pair conditioning + 3-layer MLP + bias. One block per (s,q), thread = k.
//      All weights + row-side operands are wave-uniform -> scalar loads, zero LDS
//      traffic in the MLP. LDS only for the out_pair transpose. ----
__global__ __launch_bounds__(128) void n_pair(
    const int* __restrict__ q2k, const float* __restrict__ rowproj, const float* __restrict__ colproj,
    const float* __restrict__ qrp, const int* __restrict__ quid,
    const float* __restrict__ krp, const int* __restrict__ kuid,
    const float* __restrict__ w1, const float* __restrict__ w2, const float* __restrict__ w3,
    const float* __restrict__ wpo, const float* __restrict__ wpd, const float* __restrict__ wpv,
    const float* __restrict__ wb,
    float* __restrict__ out_pair, u16* __restrict__ bias_ws)
{
  __shared__ __align__(16) float Ls[128*20];   // pitch 20 floats
  int tid = threadIdx.x;
  int sq = blockIdx.x;
  int s  = sq >> 5;
  int q  = sq & 31;
  int k  = tid;
  int sk = s*K_ + k;
  int j  = q2k[sk];

  // block-uniform row-side operands -> scalar loads
  float qx = qrp[sq*3+0], qy = qrp[sq*3+1], qz = qrp[sq*3+2];
  int   qu = quid[sq];

  float cp[16];
  *(float4*)&cp[0]  = *(const float4*)&colproj[(size_t)j*CP_ + 0];
  *(float4*)&cp[4]  = *(const float4*)&colproj[(size_t)j*CP_ + 4];
  *(float4*)&cp[8]  = *(const float4*)&colproj[(size_t)j*CP_ + 8];
  *(float4*)&cp[12] = *(const float4*)&colproj[(size_t)j*CP_ + 12];

  float p[16];
  {
    float ox = qx - krp[sk*3+0];
    float oy = qy - krp[sk*3+1];
    float oz = qz - krp[sk*3+2];
    float vf = (qu == kuid[sk]) ? 1.f : 0.f;
    float invd = vf / (1.f + ox*ox + oy*oy + oz*oz);
    #pragma unroll
    for (int c = 0; c < 16; ++c)
      p[c] = rowproj[(size_t)sq*CP_+c] + cp[c]
           + vf*(ox*wpo[c] + oy*wpo[16+c] + oz*wpo[32+c])
           + invd*wpd[c] + vf*wpv[c];
  }
  float y[16];
  #pragma unroll
  for (int c = 0; c < 16; ++c) y[c] = 0.f;
  #pragma unroll
  for (int i = 0; i < 16; ++i){
    float u = fmaxf(p[i], 0.f);
    #pragma unroll
    for (int c = 0; c < 16; ++c) y[c] += u * w1[i*16+c];   // uniform -> SGPR operand
  }
  float z[16];
  #pragma unroll
  for (int c = 0; c < 16; ++c) z[c] = 0.f;
  #pragma unroll
  for (int i = 0; i < 16; ++i){
    float u = fmaxf(y[i], 0.f);
    #pragma unroll
    for (int c = 0; c < 16; ++c) z[c] += u * w2[i*16+c];
  }
  #pragma unroll
  for (int i = 0; i < 16; ++i){
    float u = fmaxf(z[i], 0.f);
    #pragma unroll
    for (int c = 0; c < 16; ++c) p[c] += u * w3[i*16+c];
  }
  float b[4] = {0.f, 0.f, 0.f, 0.f};
  #pragma unroll
  for (int c = 0; c < 16; ++c){
    #pragma unroll
    for (int h = 0; h < 4; ++h) b[h] += p[c] * wb[c*4+h];
  }

  // bias: [s][h][q][k] layout, lanes contiguous over k
  #pragma unroll
  for (int h = 0; h < 4; ++h)
    bias_ws[(((size_t)s*H_ + h)*Q_ + q)*K_ + k] = f2b(b[h]);

  // out_pair: transpose through LDS, then fully coalesced float4 stores
  #pragma unroll
  for (int c4 = 0; c4 < 4; ++c4)
    *(float4*)&Ls[k*20 + c4*4] = make_float4(p[c4*4+0], p[c4*4+1], p[c4*4+2], p[c4*4+3]);
  __syncthreads();
  size_t obase = (size_t)sq * (K_*CP_);
  #pragma unroll
  for (int i = 0; i < 4; ++i){
    int g4 = i*128 + tid;
    int kk = g4 >> 2, c = (g4 & 3)*4;
    *(float4*)&out_pair[obase + (size_t)g4*4] = *(const float4*)&Ls[kk*20 + c];
  }
}

// ---- N6: attention. One 128-thread block per (s,h). K/V staged in LDS (pitch 36). ----
__global__ __launch_bounds__(128) void n_attn(
    const float* __restrict__ Qp, const float* __restrict__ Kp, const float* __restrict__ Vp,
    const float* __restrict__ qmask, const u16* __restrict__ bias_ws, const int* __restrict__ q2k,
    float* __restrict__ O)
{
  __shared__ float Ks[128*36];
  __shared__ float Vs[128*36];
  __shared__ float msk[128];
  __shared__ float redm[64];
  __shared__ float reds[64];
  __shared__ float Osm[32*33];

  int b = blockIdx.x;
  int s = b >> 2, h = b & 3;
  int sq0 = s * Q_;
  int base = s * K_;
  int t = threadIdx.x;

  {
    int e = t & 7, rr = t >> 3;
    #pragma unroll
    for (int it = 0; it < 8; ++it){
      int row = it*16 + rr;
      int j = q2k[base + row];
      const float4* ksrc = (const float4*)&Kp[(size_t)j*CA_ + h*DH_];
      const float4* vsrc = (const float4*)&Vp[(size_t)j*CA_ + h*DH_];
      *(float4*)&Ks[row*36 + e*4] = ksrc[e];
      *(float4*)&Vs[row*36 + e*4] = vsrc[e];
    }
    int j0 = q2k[base + t];
    msk[t] = qmask[j0];
  }

  int q  = t & 31;
  int kr = t >> 5;
  float qreg[32];
  {
    const float4* qsrc = (const float4*)&Qp[(size_t)(sq0+q)*CA_ + h*DH_];
    #pragma unroll
    for (int d4 = 0; d4 < 8; ++d4){
      float4 v = qsrc[d4];
      qreg[d4*4+0] = v.x; qreg[d4*4+1] = v.y; qreg[d4*4+2] = v.z; qreg[d4*4+3] = v.w;
    }
  }

  u32 bw[16];
  {
    const uint4* bsrc = (const uint4*)&bias_ws[(((size_t)s*H_ + h)*Q_ + q)*K_ + kr*32];
    uint4 B;
    B = bsrc[0]; bw[0]=B.x;  bw[1]=B.y;  bw[2]=B.z;  bw[3]=B.w;
    B = bsrc[1]; bw[4]=B.x;  bw[5]=B.y;  bw[6]=B.z;  bw[7]=B.w;
    B = bsrc[2]; bw[8]=B.x;  bw[9]=B.y;  bw[10]=B.z; bw[11]=B.w;
    B = bsrc[3]; bw[12]=B.x; bw[13]=B.y; bw[14]=B.z; bw[15]=B.w;
  }
  __syncthreads();

  float p[32];
  #pragma unroll
  for (int kk = 0; kk < 32; ++kk){
    int k = kr*32 + kk;
    const float* kbase = &Ks[k*36];
    float acc = 0.f;
    #pragma unroll
    for (int d4 = 0; d4 < 8; ++d4){
      float4 kv = *(const float4*)(kbase + d4*4);
      acc += qreg[d4*4+0]*kv.x + qreg[d4*4+1]*kv.y + qreg[d4*4+2]*kv.z + qreg[d4*4+3]*kv.w;
    }
    float bz = b2f((u16)((bw[kk>>1] >> ((kk&1)*16)) & 0xffffu));
    p[kk] = (msk[k] > 0.f) ? (acc + bz) : -1e9f;
  }

  float m = p[0];
  #pragma unroll
  for (int kk = 1; kk < 32; ++kk) m = fmaxf(m, p[kk]);
  m = fmaxf(m, __shfl_xor(m, 32, 64));
  int wv = t >> 6;
  if ((t & 63) < 32) redm[wv*32 + q] = m;
  __syncthreads();
  float M = fmaxf(redm[q], redm[32 + q]);

  float sm = 0.f;
  #pragma unroll
  for (int kk = 0; kk < 32; ++kk){ p[kk] = __expf(p[kk] - M); sm += p[kk]; }
  sm += __shfl_xor(sm, 32, 64);
  if ((t & 63) < 32) reds[wv*32 + q] = sm;
  __syncthreads();
  float inv = 1.f / (reds[q] + reds[32 + q]);

  float acc[32];
  #pragma unroll
  for (int d = 0; d < 32; ++d) acc[d] = 0.f;
  #pragma unroll
  for (int kk = 0; kk < 32; ++kk){
    float w = p[kk];
    const float* vbase = &Vs[(kr*32 + kk)*36];
    #pragma unroll
    for (int d4 = 0; d4 < 8; ++d4){
      float4 vv = *(const float4*)(vbase + d4*4);
      acc[d4*4+0] += w*vv.x; acc[d4*4+1] += w*vv.y; acc[d4*4+2] += w*vv.z; acc[d4*4+3] += w*vv.w;
    }
  }
  #pragma unroll
  for (int d = 0; d < 32; ++d) acc[d] += __shfl_xor(acc[d], 32, 64);
  if (t < 32){
    #pragma unroll
    for (int d = 0; d < 32; ++d) Osm[q*33 + d] = acc[d];
  }
  __syncthreads();
  if (t >= 64 && t < 96){
    #pragma unroll
    for (int d = 0; d < 32; ++d) Osm[q*33 + d] = (Osm[q*33 + d] + acc[d]) * inv;
  }
  __syncthreads();

  #pragma unroll
  for (int it = 0; it < 2; ++it){
    int idx = it*128 + t;
    int qq = idx >> 3, e = idx & 7;
    float4 v = make_float4(Osm[qq*33 + e*4 + 0], Osm[qq*33 + e*4 + 1],
                           Osm[qq*33 + e*4 + 2], Osm[qq*33 + e*4 + 3]);
    *(float4*)&O[(size_t)(sq0+qq)*CA_ + h*DH_ + e*4] = v;
  }
}

// ---- N7: queries_act = (qsc + O @ wo) * qmask. O read scalar (uniform), no LDS ----
__global__ __launch_bounds__(128) void n_qact(
    const float* __restrict__ qsc, const float* __restrict__ O, const float* __restrict__ qmask,
    const float* __restrict__ wo, float* __restrict__ qact, float* __restrict__ out_skip)
{
  int c = threadIdx.x;
  size_t r0 = (size_t)blockIdx.x * 16;
  float acc[16];
  #pragma unroll
  for (int r = 0; r < 16; ++r) acc[r] = 0.f;
  #pragma unroll 4
  for (int i = 0; i < CA_; ++i){
    float w = wo[i*CA_+c];
    #pragma unroll
    for (int r = 0; r < 16; ++r) acc[r] += O[(r0+r)*CA_+i] * w;   // uniform -> s_load
  }
  #pragma unroll
  for (int r = 0; r < 16; ++r){
    float v = (qsc[(r0+r)*CA_+c] + acc[r]) * qmask[r0+r];
    qact[(r0+r)*CA_+c] = v;
    out_skip[(r0+r)*CA_+c] = v;
  }
}

// ---- N8: proj + gather + masked mean. Gathered rows read scalar (uniform), no LDS ----
__global__ __launch_bounds__(384) void n_tok(
    const float* __restrict__ qact, const int* __restrict__ q2t, const float* __restrict__ amask,
    const float* __restrict__ wp, float* __restrict__ out_tok)
{
  int t = blockIdx.x, ct = threadIdx.x;
  int jd[D_];
  float mk[D_];
  #pragma unroll
  for (int d = 0; d < D_; ++d){
    jd[d] = q2t[t*D_ + d];          // uniform -> s_load
    mk[d] = amask[t*D_ + d];
  }
  float acc[D_];
  #pragma unroll
  for (int d = 0; d < D_; ++d) acc[d] = 0.f;
  #pragma unroll 4
  for (int i = 0; i < CA_; ++i){
    float w = wp[i*CT_ + ct];
    #pragma unroll
    for (int d = 0; d < D_; ++d) acc[d] += qact[(size_t)jd[d]*CA_ + i] * w;  // uniform -> s_load
  }
  float num = 0.f, den = 1e-10f;
  #pragma unroll
  for (int d = 0; d < D_; ++d){
    num += mk[d] * fmaxf(acc[d], 0.f);
    den += mk[d];
  }
  out_tok[(size_t)t*CT_ + ct] = num/den;
}

extern "C" void kernel_launch(void* const* d_in, const int* in_sizes, int n_in,
                              void* d_out, int out_size, void* d_ws, size_t ws_size,
                              hipStream_t stream) {
  (void)in_sizes; (void)n_in; (void)out_size; (void)ws_size;
  const float* ref_positions = (const float*)d_in[0];
  const float* ref_mask      = (const float*)d_in[1];
  const float* ref_charge    = (const float*)d_in[2];
  const float* atom_mask     = (const float*)d_in[3];
  const int*   ref_element   = (const int*)d_in[4];
  const int*   ref_chars     = (const int*)d_in[5];
  const int*   ref_uid       = (const int*)d_in[6];
  const int*   t2q           = (const int*)d_in[7];
  const int*   q2k           = (const int*)d_in[8];
  const int*   q2t           = (const int*)d_in[9];
  const float* w_ref_pos     = (const float*)d_in[10];
  const float* w_ref_mask    = (const float*)d_in[11];
  const float* w_ref_element = (const float*)d_in[12];
  const float* w_ref_charge  = (const float*)d_in[13];
  const float* w_ref_name    = (const float*)d_in[14];
  const float* w_s2p_row1    = (const float*)d_in[15];
  const float* w_s2p_col1    = (const float*)d_in[16];
  const float* w_pair_off1   = (const float*)d_in[17];
  const float* w_pair_dist1  = (const float*)d_in[18];
  const float* w_pair_valid  = (const float*)d_in[19];
  const float* w_mlp1        = (const float*)d_in[20];
  const float* w_mlp2        = (const float*)d_in[21];
  const float* w_mlp3        = (const float*)d_in[22];
  const float* wq            = (const float*)d_in[23];
  const float* wk            = (const float*)d_in[24];
  const float* wv            = (const float*)d_in[25];
  const float* wb            = (const float*)d_in[26];
  const float* wo            = (const float*)d_in[27];
  const float* w_proj        = (const float*)d_in[28];

  char* ws = (char*)d_ws;
  float* qsc     = (float*)(ws + 0);
  float* qmask   = (float*)(ws + 9437184);
  float* qrp     = (float*)(ws + 9732096);
  int*   quid    = (int*)  (ws + 9953280);
  float* krp     = (float*)(ws + 10027008);
  int*   kuid    = (int*)  (ws + 10911744);
  float* rowproj = (float*)(ws + 11206656);
  float* colproj = (float*)(ws + 12386304);
  float* Qp      = (float*)(ws + 13565952);
  float* Kp      = (float*)(ws + 23003136);
  float* Vp      = (float*)(ws + 32440320);
  float* O       = (float*)(ws + 41877504);
  float* qact    = (float*)(ws + 51314688);
  u16*   biasws  = (u16*)  (ws + 60751872);

  float* out = (float*)d_out;
  float* out_tok   = out + 0;
  float* out_skip  = out + 294912;
  float* out_qmask = out + 2654208;
  float* out_qsc   = out + 2672640;
  float* out_kmask = out + 5031936;
  float* out_ksc   = out + 5105664;
  float* out_pair  = out + 14542848;

  hipLaunchKernelGGL(n_qsc, dim3(SQ_), dim3(128), 0, stream,
      ref_positions, ref_mask, ref_charge, atom_mask, ref_element, ref_chars, ref_uid, t2q,
      w_ref_pos, w_ref_mask, w_ref_element, w_ref_charge, w_ref_name,
      qsc, qmask, qrp, quid, out_qsc, out_qmask);
  hipLaunchKernelGGL(n_keys, dim3(SK_/4), dim3(128), 0, stream,
      qsc, qmask, qrp, ref_uid, q2k, krp, kuid, out_ksc, out_kmask);
  hipLaunchKernelGGL(n_qkv, dim3(SQ_/16), dim3(128), 0, stream,
      qsc, wq, wk, wv, Qp, Kp, Vp);
  hipLaunchKernelGGL(n_proj16b, dim3(SQ_/4), dim3(128), 0, stream,
      qsc, w_s2p_row1, w_s2p_col1, rowproj, colproj);
  hipLaunchKernelGGL(n_pair, dim3(SQ_), dim3(128), 0, stream,
      q2k, rowproj, colproj, qrp, quid, krp, kuid,
      w_mlp1, w_mlp2, w_mlp3, w_pair_off1, w_pair_dist1, w_pair_valid, wb,
      out_pair, biasws);
  hipLaunchKernelGGL(n_attn, dim3(S_*H_), dim3(128), 0, stream,
      Qp, Kp, Vp, qmask, biasws, q2k, O);
  hipLaunchKernelGGL(n_qact, dim3(SQ_/16), dim3(128), 0, stream,
      qsc, O, qmask, wo, qact, out_skip);
  hipLaunchKernelGGL(n_tok, dim3(T_), dim3(384), 0, stream,
      qact, q2t, atom_mask, w_proj, out_tok);
}

// Round 4
// 607.570 us; speedup vs baseline: 1.0413x; 1.0413x over previous
//
#include <hip/hip_runtime.h>

typedef unsigned short u16;
typedef unsigned int u32;

#define T_ 768
#define D_ 24
#define S_ 576
#define Q_ 32
#define K_ 128
#define CA_ 128
#define CP_ 16
#define CT_ 384
#define H_ 4
#define DH_ 32
#define SQ_ (S_*Q_)
#define SK_ (S_*K_)

__device__ __forceinline__ float b2f(u16 u){ return __uint_as_float(((u32)u)<<16); }
__device__ __forceinline__ u16 f2b(float f){ u32 x=__float_as_uint(f); return (u16)((x + 0x7fffu + ((x>>16)&1u))>>16); }

// ---- N1: per-atom conditioning gathered to query slots; also qrp/quid ----
__global__ __launch_bounds__(128) void n_qsc(
    const float* __restrict__ pos, const float* __restrict__ rmask, const float* __restrict__ charge,
    const float* __restrict__ amask, const int* __restrict__ elem, const int* __restrict__ chars,
    const int* __restrict__ uid, const int* __restrict__ t2q,
    const float* __restrict__ w_pos, const float* __restrict__ w_mask, const float* __restrict__ w_elem,
    const float* __restrict__ w_chg, const float* __restrict__ w_name,
    float* __restrict__ qsc, float* __restrict__ qmask, float* __restrict__ qrp, int* __restrict__ quid,
    float* __restrict__ out_qsc, float* __restrict__ out_qmask)
{
  int slot = blockIdx.x, ch = threadIdx.x;
  int a = t2q[slot];
  float p0 = pos[a*3+0], p1 = pos[a*3+1], p2 = pos[a*3+2];
  float m  = rmask[a];
  float cg = asinhf(charge[a]);
  int e  = elem[a];
  int c0 = chars[a*4+0], c1 = chars[a*4+1], c2 = chars[a*4+2], c3 = chars[a*4+3];
  float v = p0*w_pos[0*CA_+ch] + p1*w_pos[1*CA_+ch] + p2*w_pos[2*CA_+ch];
  v += m * w_mask[ch];
  v += w_elem[e*CA_+ch];
  v += cg * w_chg[ch];
  v += w_name[(0*64+c0)*CA_+ch] + w_name[(1*64+c1)*CA_+ch]
     + w_name[(2*64+c2)*CA_+ch] + w_name[(3*64+c3)*CA_+ch];
  v *= m;
  qsc[(size_t)slot*CA_+ch] = v;
  out_qsc[(size_t)slot*CA_+ch] = v;
  if (ch < 3) qrp[slot*3+ch] = pos[a*3+ch];
  if (ch == 0){
    float am = amask[a];
    qmask[slot] = am;
    out_qmask[slot] = am;
    quid[slot] = uid[a];
  }
}

// ---- N2: key-space gathers. 4 rows/block, one float4 per thread ----
__global__ __launch_bounds__(128) void n_keys(
    const float* __restrict__ qsc, const float* __restrict__ qmask, const float* __restrict__ qrp,
    const int* __restrict__ uid, const int* __restrict__ q2k,
    float* __restrict__ krp, int* __restrict__ kuid,
    float* __restrict__ out_ksc, float* __restrict__ out_kmask)
{
  int r = threadIdx.x >> 5;
  int e = threadIdx.x & 31;
  int sk = blockIdx.x*4 + r;
  int j = q2k[sk];
  *(float4*)&out_ksc[(size_t)sk*CA_ + e*4] = *(const float4*)&qsc[(size_t)j*CA_ + e*4];
  if (e < 3) krp[sk*3+e] = qrp[j*3+e];
  if (e == 0){
    out_kmask[sk] = qmask[j];
    kuid[sk] = uid[j];
  }
}

// ---- N3: fused QKV projection. Block = 16 rows, 128 threads (thread = out col). ----
__global__ __launch_bounds__(128) void n_qkv(
    const float* __restrict__ X, const float* __restrict__ wq, const float* __restrict__ wk,
    const float* __restrict__ wv, float* __restrict__ Qp, float* __restrict__ Kp, float* __restrict__ Vp)
{
  int c = threadIdx.x;
  size_t r0 = (size_t)blockIdx.x * 16;
  float aq[16], ak[16], av[16];
  #pragma unroll
  for (int r = 0; r < 16; ++r){ aq[r] = 0.f; ak[r] = 0.f; av[r] = 0.f; }
  #pragma unroll 4
  for (int i = 0; i < CA_; ++i){
    float q = wq[i*CA_+c];
    float k = wk[i*CA_+c];
    float v = wv[i*CA_+c];
    #pragma unroll
    for (int r = 0; r < 16; ++r){
      float x = X[(r0+r)*CA_ + i];     // uniform -> s_load
      aq[r] += x * q;
      ak[r] += x * k;
      av[r] += x * v;
    }
  }
  #pragma unroll
  for (int r = 0; r < 16; ++r){
    Qp[(r0+r)*CA_+c] = aq[r] * 0.17677669529663687f;
    Kp[(r0+r)*CA_+c] = ak[r];
    Vp[(r0+r)*CA_+c] = av[r];
  }
}

// ---- N4: fused row+col 128->16 relu-linear. Block = 4 rows x 32 cols (16 row, 16 col) ----
__global__ __launch_bounds__(128) void n_proj16b(
    const float* __restrict__ X, const float* __restrict__ Wr, const float* __restrict__ Wc,
    float* __restrict__ Yr, float* __restrict__ Yc)
{
  int row = blockIdx.x*4 + (threadIdx.x >> 5);
  int c = threadIdx.x & 31;
  const float* W = (c < 16) ? Wr : Wc;
  float* Y = (c < 16) ? Yr : Yc;
  int cc = c & 15;
  float acc = 0.f;
  for (int i = 0; i < CA_; ++i)
    acc += fmaxf(X[(size_t)row*CA_+i], 0.f) * W[i*CP_+cc];
  Y[(size_t)row*CP_+cc] = acc;
}

// ---- N5: pair conditioning + 3-layer MLP + bias.
//      Block = (s, group of 4 q); thread = k. Weights in LDS, read ONCE per 4 rows
//      (amortizes the LDS-pipe bottleneck 4x). Key-side operands amortized 4x too.
//      Direct float4 stores (store coalescing proven irrelevant in r2). ----
__global__ __launch_bounds__(128) void n_pair(
    const int* __restrict__ q2k, const float* __restrict__ rowproj, const float* __restrict__ colproj,
    const float* __restrict__ qrp, const int* __restrict__ quid,
    const float* __restrict__ krp, const int* __restrict__ kuid,
    const float* __restrict__ w1, const float* __restrict__ w2, const float* __restrict__ w3,
    const float* __restrict__ wpo, const float* __restrict__ wpd, const float* __restrict__ wpv,
    const float* __restrict__ wb,
    float* __restrict__ out_pair, u16* __restrict__ bias_ws)
{
  __shared__ float w1s[256], w2s[256], w3s[256], wbs[64], wpos[48], wpds[16], wpvs[16];
  int tid = threadIdx.x;
  for (int e = tid; e < 256; e += 128){ w1s[e] = w1[e]; w2s[e] = w2[e]; w3s[e] = w3[e]; }
  if (tid < 64) wbs[tid] = wb[tid];
  if (tid < 48) wpos[tid] = wpo[tid];
  if (tid < 16){ wpds[tid] = wpd[tid]; wpvs[tid] = wpv[tid]; }
  __syncthreads();

  int bk = blockIdx.x;
  int s  = bk >> 3;
  int qg = bk & 7;            // 4-q group
  int k  = tid;
  int sk = s*K_ + k;
  int j  = q2k[sk];

  // key-side operands: loaded once, reused for 4 q rows
  float kx = krp[sk*3+0], ky = krp[sk*3+1], kz = krp[sk*3+2];
  int   ku = kuid[sk];
  float cp[16];
  *(float4*)&cp[0]  = *(const float4*)&colproj[(size_t)j*CP_ + 0];
  *(float4*)&cp[4]  = *(const float4*)&colproj[(size_t)j*CP_ + 4];
  *(float4*)&cp[8]  = *(const float4*)&colproj[(size_t)j*CP_ + 8];
  *(float4*)&cp[12] = *(const float4*)&colproj[(size_t)j*CP_ + 12];

  float p[4][16];
  #pragma unroll
  for (int r = 0; r < 4; ++r){
    int sq = s*Q_ + qg*4 + r;
    float rp[16];
    *(float4*)&rp[0]  = *(const float4*)&rowproj[(size_t)sq*CP_ + 0];
    *(float4*)&rp[4]  = *(const float4*)&rowproj[(size_t)sq*CP_ + 4];
    *(float4*)&rp[8]  = *(const float4*)&rowproj[(size_t)sq*CP_ + 8];
    *(float4*)&rp[12] = *(const float4*)&rowproj[(size_t)sq*CP_ + 12];
    float ox = qrp[sq*3+0] - kx;
    float oy = qrp[sq*3+1] - ky;
    float oz = qrp[sq*3+2] - kz;
    float vf = (quid[sq] == ku) ? 1.f : 0.f;
    float invd = vf / (1.f + ox*ox + oy*oy + oz*oz);
    #pragma unroll
    for (int c = 0; c < 16; ++c)
      p[r][c] = rp[c] + cp[c]
              + vf*(ox*wpos[c] + oy*wpos[16+c] + oz*wpos[32+c])
              + invd*wpds[c] + vf*wpvs[c];
  }

  float y[4][16];
  #pragma unroll
  for (int r = 0; r < 4; ++r)
    #pragma unroll
    for (int c = 0; c < 16; ++c) y[r][c] = 0.f;
  #pragma unroll
  for (int i = 0; i < 16; ++i){
    float u0 = fmaxf(p[0][i], 0.f);
    float u1 = fmaxf(p[1][i], 0.f);
    float u2 = fmaxf(p[2][i], 0.f);
    float u3 = fmaxf(p[3][i], 0.f);
    #pragma unroll
    for (int c4 = 0; c4 < 4; ++c4){
      float4 w = *(const float4*)&w1s[i*16 + c4*4];
      y[0][c4*4+0] += u0*w.x; y[0][c4*4+1] += u0*w.y; y[0][c4*4+2] += u0*w.z; y[0][c4*4+3] += u0*w.w;
      y[1][c4*4+0] += u1*w.x; y[1][c4*4+1] += u1*w.y; y[1][c4*4+2] += u1*w.z; y[1][c4*4+3] += u1*w.w;
      y[2][c4*4+0] += u2*w.x; y[2][c4*4+1] += u2*w.y; y[2][c4*4+2] += u2*w.z; y[2][c4*4+3] += u2*w.w;
      y[3][c4*4+0] += u3*w.x; y[3][c4*4+1] += u3*w.y; y[3][c4*4+2] += u3*w.z; y[3][c4*4+3] += u3*w.w;
    }
  }

  float z[4][16];
  #pragma unroll
  for (int r = 0; r < 4; ++r)
    #pragma unroll
    for (int c = 0; c < 16; ++c) z[r][c] = 0.f;
  #pragma unroll
  for (int i = 0; i < 16; ++i){
    float u0 = fmaxf(y[0][i], 0.f);
    float u1 = fmaxf(y[1][i], 0.f);
    float u2 = fmaxf(y[2][i], 0.f);
    float u3 = fmaxf(y[3][i], 0.f);
    #pragma unroll
    for (int c4 = 0; c4 < 4; ++c4){
      float4 w = *(const float4*)&w2s[i*16 + c4*4];
      z[0][c4*4+0] += u0*w.x; z[0][c4*4+1] += u0*w.y; z[0][c4*4+2] += u0*w.z; z[0][c4*4+3] += u0*w.w;
      z[1][c4*4+0] += u1*w.x; z[1][c4*4+1] += u1*w.y; z[1][c4*4+2] += u1*w.z; z[1][c4*4+3] += u1*w.w;
      z[2][c4*4+0] += u2*w.x; z[2][c4*4+1] += u2*w.y; z[2][c4*4+2] += u2*w.z; z[2][c4*4+3] += u2*w.w;
      z[3][c4*4+0] += u3*w.x; z[3][c4*4+1] += u3*w.y; z[3][c4*4+2] += u3*w.z; z[3][c4*4+3] += u3*w.w;
    }
  }

  #pragma unroll
  for (int i = 0; i < 16; ++i){
    float u0 = fmaxf(z[0][i], 0.f);
    float u1 = fmaxf(z[1][i], 0.f);
    float u2 = fmaxf(z[2][i], 0.f);
    float u3 = fmaxf(z[3][i], 0.f);
    #pragma unroll
    for (int c4 = 0; c4 < 4; ++c4){
      float4 w = *(const float4*)&w3s[i*16 + c4*4];
      p[0][c4*4+0] += u0*w.x; p[0][c4*4+1] += u0*w.y; p[0][c4*4+2] += u0*w.z; p[0][c4*4+3] += u0*w.w;
      p[1][c4*4+0] += u1*w.x; p[1][c4*4+1] += u1*w.y; p[1][c4*4+2] += u1*w.z; p[1][c4*4+3] += u1*w.w;
      p[2][c4*4+0] += u2*w.x; p[2][c4*4+1] += u2*w.y; p[2][c4*4+2] += u2*w.z; p[2][c4*4+3] += u2*w.w;
      p[3][c4*4+0] += u3*w.x; p[3][c4*4+1] += u3*w.y; p[3][c4*4+2] += u3*w.z; p[3][c4*4+3] += u3*w.w;
    }
  }

  #pragma unroll
  for (int r = 0; r < 4; ++r){
    int q  = qg*4 + r;
    int sq = s*Q_ + q;
    float b[4] = {0.f, 0.f, 0.f, 0.f};
    #pragma unroll
    for (int c = 0; c < 16; ++c){
      #pragma unroll
      for (int h = 0; h < 4; ++h) b[h] += p[r][c] * wbs[c*4+h];
    }
    #pragma unroll
    for (int h = 0; h < 4; ++h)
      bias_ws[(((size_t)s*H_ + h)*Q_ + q)*K_ + k] = f2b(b[h]);
    size_t obase = ((size_t)sq*K_ + k)*CP_;
    #pragma unroll
    for (int c4 = 0; c4 < 4; ++c4)
      *(float4*)&out_pair[obase + c4*4] =
        make_float4(p[r][c4*4+0], p[r][c4*4+1], p[r][c4*4+2], p[r][c4*4+3]);
  }
}

// ---- N6: attention. One 128-thread block per (s,h). K/V staged in LDS (pitch 36). ----
__global__ __launch_bounds__(128) void n_attn(
    const float* __restrict__ Qp, const float* __restrict__ Kp, const float* __restrict__ Vp,
    const float* __restrict__ qmask, const u16* __restrict__ bias_ws, const int* __restrict__ q2k,
    float* __restrict__ O)
{
  __shared__ float Ks[128*36];
  __shared__ float Vs[128*36];
  __shared__ float msk[128];
  __shared__ float redm[64];
  __shared__ float reds[64];
  __shared__ float Osm[32*33];

  int b = blockIdx.x;
  int s = b >> 2, h = b & 3;
  int sq0 = s * Q_;
  int base = s * K_;
  int t = threadIdx.x;

  {
    int e = t & 7, rr = t >> 3;
    #pragma unroll
    for (int it = 0; it < 8; ++it){
      int row = it*16 + rr;
      int j = q2k[base + row];
      const float4* ksrc = (const float4*)&Kp[(size_t)j*CA_ + h*DH_];
      const float4* vsrc = (const float4*)&Vp[(size_t)j*CA_ + h*DH_];
      *(float4*)&Ks[row*36 + e*4] = ksrc[e];
      *(float4*)&Vs[row*36 + e*4] = vsrc[e];
    }
    int j0 = q2k[base + t];
    msk[t] = qmask[j0];
  }

  int q  = t & 31;
  int kr = t >> 5;
  float qreg[32];
  {
    const float4* qsrc = (const float4*)&Qp[(size_t)(sq0+q)*CA_ + h*DH_];
    #pragma unroll
    for (int d4 = 0; d4 < 8; ++d4){
      float4 v = qsrc[d4];
      qreg[d4*4+0] = v.x; qreg[d4*4+1] = v.y; qreg[d4*4+2] = v.z; qreg[d4*4+3] = v.w;
    }
  }

  u32 bw[16];
  {
    const uint4* bsrc = (const uint4*)&bias_ws[(((size_t)s*H_ + h)*Q_ + q)*K_ + kr*32];
    uint4 B;
    B = bsrc[0]; bw[0]=B.x;  bw[1]=B.y;  bw[2]=B.z;  bw[3]=B.w;
    B = bsrc[1]; bw[4]=B.x;  bw[5]=B.y;  bw[6]=B.z;  bw[7]=B.w;
    B = bsrc[2]; bw[8]=B.x;  bw[9]=B.y;  bw[10]=B.z; bw[11]=B.w;
    B = bsrc[3]; bw[12]=B.x; bw[13]=B.y; bw[14]=B.z; bw[15]=B.w;
  }
  __syncthreads();

  float p[32];
  #pragma unroll
  for (int kk = 0; kk < 32; ++kk){
    int k = kr*32 + kk;
    const float* kbase = &Ks[k*36];
    float acc = 0.f;
    #pragma unroll
    for (int d4 = 0; d4 < 8; ++d4){
      float4 kv = *(const float4*)(kbase + d4*4);
      acc += qreg[d4*4+0]*kv.x + qreg[d4*4+1]*kv.y + qreg[d4*4+2]*kv.z + qreg[d4*4+3]*kv.w;
    }
    float bz = b2f((u16)((bw[kk>>1] >> ((kk&1)*16)) & 0xffffu));
    p[kk] = (msk[k] > 0.f) ? (acc + bz) : -1e9f;
  }

  float m = p[0];
  #pragma unroll
  for (int kk = 1; kk < 32; ++kk) m = fmaxf(m, p[kk]);
  m = fmaxf(m, __shfl_xor(m, 32, 64));
  int wv = t >> 6;
  if ((t & 63) < 32) redm[wv*32 + q] = m;
  __syncthreads();
  float M = fmaxf(redm[q], redm[32 + q]);

  float sm = 0.f;
  #pragma unroll
  for (int kk = 0; kk < 32; ++kk){ p[kk] = __expf(p[kk] - M); sm += p[kk]; }
  sm += __shfl_xor(sm, 32, 64);
  if ((t & 63) < 32) reds[wv*32 + q] = sm;
  __syncthreads();
  float inv = 1.f / (reds[q] + reds[32 + q]);

  float acc[32];
  #pragma unroll
  for (int d = 0; d < 32; ++d) acc[d] = 0.f;
  #pragma unroll
  for (int kk = 0; kk < 32; ++kk){
    float w = p[kk];
    const float* vbase = &Vs[(kr*32 + kk)*36];
    #pragma unroll
    for (int d4 = 0; d4 < 8; ++d4){
      float4 vv = *(const float4*)(vbase + d4*4);
      acc[d4*4+0] += w*vv.x; acc[d4*4+1] += w*vv.y; acc[d4*4+2] += w*vv.z; acc[d4*4+3] += w*vv.w;
    }
  }
  #pragma unroll
  for (int d = 0; d < 32; ++d) acc[d] += __shfl_xor(acc[d], 32, 64);
  if (t < 32){
    #pragma unroll
    for (int d = 0; d < 32; ++d) Osm[q*33 + d] = acc[d];
  }
  __syncthreads();
  if (t >= 64 && t < 96){
    #pragma unroll
    for (int d = 0; d < 32; ++d) Osm[q*33 + d] = (Osm[q*33 + d] + acc[d]) * inv;
  }
  __syncthreads();

  #pragma unroll
  for (int it = 0; it < 2; ++it){
    int idx = it*128 + t;
    int qq = idx >> 3, e = idx & 7;
    float4 v = make_float4(Osm[qq*33 + e*4 + 0], Osm[qq*33 + e*4 + 1],
                           Osm[qq*33 + e*4 + 2], Osm[qq*33 + e*4 + 3]);
    *(float4*)&O[(size_t)(sq0+qq)*CA_ + h*DH_ + e*4] = v;
  }
}

// ---- N7: queries_act = (qsc + O @ wo) * qmask. O read scalar (uniform), no LDS ----
__global__ __launch_bounds__(128) void n_qact(
    const float* __restrict__ qsc, const float* __restrict__ O, const float* __restrict__ qmask,
    const float* __restrict__ wo, float* __restrict__ qact, float* __restrict__ out_skip)
{
  int c = threadIdx.x;
  size_t r0 = (size_t)blockIdx.x * 16;
  float acc[16];
  #pragma unroll
  for (int r = 0; r < 16; ++r) acc[r] = 0.f;
  #pragma unroll 4
  for (int i = 0; i < CA_; ++i){
    float w = wo[i*CA_+c];
    #pragma unroll
    for (int r = 0; r < 16; ++r) acc[r] += O[(r0+r)*CA_+i] * w;   // uniform -> s_load
  }
  #pragma unroll
  for (int r = 0; r < 16; ++r){
    float v = (qsc[(r0+r)*CA_+c] + acc[r]) * qmask[r0+r];
    qact[(r0+r)*CA_+c] = v;
    out_skip[(r0+r)*CA_+c] = v;
  }
}

// ---- N8: proj + gather + masked mean. Gathered rows read scalar (uniform), no LDS ----
__global__ __launch_bounds__(384) void n_tok(
    const float* __restrict__ qact, const int* __restrict__ q2t, const float* __restrict__ amask,
    const float* __restrict__ wp, float* __restrict__ out_tok)
{
  int t = blockIdx.x, ct = threadIdx.x;
  int jd[D_];
  float mk[D_];
  #pragma unroll
  for (int d = 0; d < D_; ++d){
    jd[d] = q2t[t*D_ + d];          // uniform -> s_load
    mk[d] = amask[t*D_ + d];
  }
  float acc[D_];
  #pragma unroll
  for (int d = 0; d < D_; ++d) acc[d] = 0.f;
  #pragma unroll 4
  for (int i = 0; i < CA_; ++i){
    float w = wp[i*CT_ + ct];
    #pragma unroll
    for (int d = 0; d < D_; ++d) acc[d] += qact[(size_t)jd[d]*CA_ + i] * w;  // uniform -> s_load
  }
  float num = 0.f, den = 1e-10f;
  #pragma unroll
  for (int d = 0; d < D_; ++d){
    num += mk[d] * fmaxf(acc[d], 0.f);
    den += mk[d];
  }
  out_tok[(size_t)t*CT_ + ct] = num/den;
}

extern "C" void kernel_launch(void* const* d_in, const int* in_sizes, int n_in,
                              void* d_out, int out_size, void* d_ws, size_t ws_size,
                              hipStream_t stream) {
  (void)in_sizes; (void)n_in; (void)out_size; (void)ws_size;
  const float* ref_positions = (const float*)d_in[0];
  const float* ref_mask      = (const float*)d_in[1];
  const float* ref_charge    = (const float*)d_in[2];
  const float* atom_mask     = (const float*)d_in[3];
  const int*   ref_element   = (const int*)d_in[4];
  const int*   ref_chars     = (const int*)d_in[5];
  const int*   ref_uid       = (const int*)d_in[6];
  const int*   t2q           = (const int*)d_in[7];
  const int*   q2k           = (const int*)d_in[8];
  const int*   q2t           = (const int*)d_in[9];
  const float* w_ref_pos     = (const float*)d_in[10];
  const float* w_ref_mask    = (const float*)d_in[11];
  const float* w_ref_element = (const float*)d_in[12];
  const float* w_ref_charge  = (const float*)d_in[13];
  const float* w_ref_name    = (const float*)d_in[14];
  const float* w_s2p_row1    = (const float*)d_in[15];
  const float* w_s2p_col1    = (const float*)d_in[16];
  const float* w_pair_off1   = (const float*)d_in[17];
  const float* w_pair_dist1  = (const float*)d_in[18];
  const float* w_pair_valid  = (const float*)d_in[19];
  const float* w_mlp1        = (const float*)d_in[20];
  const float* w_mlp2        = (const float*)d_in[21];
  const float* w_mlp3        = (const float*)d_in[22];
  const float* wq            = (const float*)d_in[23];
  const float* wk            = (const float*)d_in[24];
  const float* wv            = (const float*)d_in[25];
  const float* wb            = (const float*)d_in[26];
  const float* wo            = (const float*)d_in[27];
  const float* w_proj        = (const float*)d_in[28];

  char* ws = (char*)d_ws;
  float* qsc     = (float*)(ws + 0);
  float* qmask   = (float*)(ws + 9437184);
  float* qrp     = (float*)(ws + 9732096);
  int*   quid    = (int*)  (ws + 9953280);
  float* krp     = (float*)(ws + 10027008);
  int*   kuid    = (int*)  (ws + 10911744);
  float* rowproj = (float*)(ws + 11206656);
  float* colproj = (float*)(ws + 12386304);
  float* Qp      = (float*)(ws + 13565952);
  float* Kp      = (float*)(ws + 23003136);
  float* Vp      = (float*)(ws + 32440320);
  float* O       = (float*)(ws + 41877504);
  float* qact    = (float*)(ws + 51314688);
  u16*   biasws  = (u16*)  (ws + 60751872);

  float* out = (float*)d_out;
  float* out_tok   = out + 0;
  float* out_skip  = out + 294912;
  float* out_qmask = out + 2654208;
  float* out_qsc   = out + 2672640;
  float* out_kmask = out + 5031936;
  float* out_ksc   = out + 5105664;
  float* out_pair  = out + 14542848;

  hipLaunchKernelGGL(n_qsc, dim3(SQ_), dim3(128), 0, stream,
      ref_positions, ref_mask, ref_charge, atom_mask, ref_element, ref_chars, ref_uid, t2q,
      w_ref_pos, w_ref_mask, w_ref_element, w_ref_charge, w_ref_name,
      qsc, qmask, qrp, quid, out_qsc, out_qmask);
  hipLaunchKernelGGL(n_keys, dim3(SK_/4), dim3(128), 0, stream,
      qsc, qmask, qrp, ref_uid, q2k, krp, kuid, out_ksc, out_kmask);
  hipLaunchKernelGGL(n_qkv, dim3(SQ_/16), dim3(128), 0, stream,
      qsc, wq, wk, wv, Qp, Kp, Vp);
  hipLaunchKernelGGL(n_proj16b, dim3(SQ_/4), dim3(128), 0, stream,
      qsc, w_s2p_row1, w_s2p_col1, rowproj, colproj);
  hipLaunchKernelGGL(n_pair, dim3(S_*8), dim3(128), 0, stream,
      q2k, rowproj, colproj, qrp, quid, krp, kuid,
      w_mlp1, w_mlp2, w_mlp3, w_pair_off1, w_pair_dist1, w_pair_valid, wb,
      out_pair, biasws);
  hipLaunchKernelGGL(n_attn, dim3(S_*H_), dim3(128), 0, stream,
      Qp, Kp, Vp, qmask, biasws, q2k, O);
  hipLaunchKernelGGL(n_qact, dim3(SQ_/16), dim3(128), 0, stream,
      qsc, O, qmask, wo, qact, out_skip);
  hipLaunchKernelGGL(n_tok, dim3(T_), dim3(384), 0, stream,
      qact, q2t, atom_mask, w_proj, out_tok);
}

// Round 7
// 562.459 us; speedup vs baseline: 1.1248x; 1.0802x over previous
//
#include <hip/hip_runtime.h>

typedef unsigned short u16;
typedef unsigned int u32;
typedef short bf16x8 __attribute__((ext_vector_type(8)));
typedef float f32x16 __attribute__((ext_vector_type(16)));

#define T_ 768
#define D_ 24
#define S_ 576
#define Q_ 32
#define K_ 128
#define CA_ 128
#define CP_ 16
#define CT_ 384
#define H_ 4
#define DH_ 32
#define SQ_ (S_*Q_)
#define SK_ (S_*K_)

__device__ __forceinline__ float b2f(u16 u){ return __uint_as_float(((u32)u)<<16); }
__device__ __forceinline__ u16 f2b(float f){ u32 x=__float_as_uint(f); return (u16)((x + 0x7fffu + ((x>>16)&1u))>>16); }

// Compiler-order fence for intra-wave LDS exchange (no runtime cost).
// DS pipe is in-order per wave; these stop hipcc from reordering the
// cross-lane ds_write/ds_read pairs (rule #18-class hazard).
__device__ __forceinline__ void wave_fence(){
  __builtin_amdgcn_sched_barrier(0);
  __builtin_amdgcn_wave_barrier();
  __builtin_amdgcn_sched_barrier(0);
}

// ---- N1: per-atom conditioning gathered to query slots; also qrp/quid ----
__global__ __launch_bounds__(128) void n_qsc(
    const float* __restrict__ pos, const float* __restrict__ rmask, const float* __restrict__ charge,
    const float* __restrict__ amask, const int* __restrict__ elem, const int* __restrict__ chars,
    const int* __restrict__ uid, const int* __restrict__ t2q,
    const float* __restrict__ w_pos, const float* __restrict__ w_mask, const float* __restrict__ w_elem,
    const float* __restrict__ w_chg, const float* __restrict__ w_name,
    float* __restrict__ qsc, float* __restrict__ qmask, float* __restrict__ qrp, int* __restrict__ quid,
    float* __restrict__ out_qsc, float* __restrict__ out_qmask)
{
  int slot = blockIdx.x, ch = threadIdx.x;
  int a = t2q[slot];
  float p0 = pos[a*3+0], p1 = pos[a*3+1], p2 = pos[a*3+2];
  float m  = rmask[a];
  float cg = asinhf(charge[a]);
  int e  = elem[a];
  int c0 = chars[a*4+0], c1 = chars[a*4+1], c2 = chars[a*4+2], c3 = chars[a*4+3];
  float v = p0*w_pos[0*CA_+ch] + p1*w_pos[1*CA_+ch] + p2*w_pos[2*CA_+ch];
  v += m * w_mask[ch];
  v += w_elem[e*CA_+ch];
  v += cg * w_chg[ch];
  v += w_name[(0*64+c0)*CA_+ch] + w_name[(1*64+c1)*CA_+ch]
     + w_name[(2*64+c2)*CA_+ch] + w_name[(3*64+c3)*CA_+ch];
  v *= m;
  qsc[(size_t)slot*CA_+ch] = v;
  out_qsc[(size_t)slot*CA_+ch] = v;
  if (ch < 3) qrp[slot*3+ch] = pos[a*3+ch];
  if (ch == 0){
    float am = amask[a];
    qmask[slot] = am;
    out_qmask[slot] = am;
    quid[slot] = uid[a];
  }
}

// ---- N2: key-space gathers. 4 rows/block, one float4 per thread ----
__global__ __launch_bounds__(128) void n_keys(
    const float* __restrict__ qsc, const float* __restrict__ qmask, const float* __restrict__ qrp,
    const int* __restrict__ uid, const int* __restrict__ q2k,
    float* __restrict__ krp, int* __restrict__ kuid,
    float* __restrict__ out_ksc, float* __restrict__ out_kmask)
{
  int r = threadIdx.x >> 5;
  int e = threadIdx.x & 31;
  int sk = blockIdx.x*4 + r;
  int j = q2k[sk];
  *(float4*)&out_ksc[(size_t)sk*CA_ + e*4] = *(const float4*)&qsc[(size_t)j*CA_ + e*4];
  if (e < 3) krp[sk*3+e] = qrp[j*3+e];
  if (e == 0){
    out_kmask[sk] = qmask[j];
    kuid[sk] = uid[j];
  }
}

// ---- N3: fused QKV projection ----
__global__ __launch_bounds__(128) void n_qkv(
    const float* __restrict__ X, const float* __restrict__ wq, const float* __restrict__ wk,
    const float* __restrict__ wv, float* __restrict__ Qp, float* __restrict__ Kp, float* __restrict__ Vp)
{
  int c = threadIdx.x;
  size_t r0 = (size_t)blockIdx.x * 16;
  float aq[16], ak[16], av[16];
  #pragma unroll
  for (int r = 0; r < 16; ++r){ aq[r] = 0.f; ak[r] = 0.f; av[r] = 0.f; }
  #pragma unroll 4
  for (int i = 0; i < CA_; ++i){
    float q = wq[i*CA_+c];
    float k = wk[i*CA_+c];
    float v = wv[i*CA_+c];
    #pragma unroll
    for (int r = 0; r < 16; ++r){
      float x = X[(r0+r)*CA_ + i];
      aq[r] += x * q;
      ak[r] += x * k;
      av[r] += x * v;
    }
  }
  #pragma unroll
  for (int r = 0; r < 16; ++r){
    Qp[(r0+r)*CA_+c] = aq[r] * 0.17677669529663687f;
    Kp[(r0+r)*CA_+c] = ak[r];
    Vp[(r0+r)*CA_+c] = av[r];
  }
}

// ---- N4: fused row+col 128->16 relu-linear ----
__global__ __launch_bounds__(128) void n_proj16b(
    const float* __restrict__ X, const float* __restrict__ Wr, const float* __restrict__ Wc,
    float* __restrict__ Yr, float* __restrict__ Yc)
{
  int row = blockIdx.x*4 + (threadIdx.x >> 5);
  int c = threadIdx.x & 31;
  const float* W = (c < 16) ? Wr : Wc;
  float* Y = (c < 16) ? Yr : Yc;
  int cc = c & 15;
  float acc = 0.f;
  for (int i = 0; i < CA_; ++i)
    acc += fmaxf(X[(size_t)row*CA_+i], 0.f) * W[i*CP_+cc];
  Y[(size_t)row*CP_+cc] = acc;
}

// ---- N5: pair conditioning + MLP via bf16 MFMA (32x32x16) + bias.
//      Block = (s, q-group-of-8), 128 threads = 2 waves, each wave owns 4 q rows.
//      Weights in per-lane B-fragments (loaded ONCE). Inter-layer 32x32 transpose
//      via per-wave padded LDS tile X[ch*33 + point] with wave_fence() ordering
//      (DS pipe is in-order per wave; fence pins compiler order). ----
__global__ __launch_bounds__(128) void n_pair(
    const int* __restrict__ q2k, const float* __restrict__ rowproj, const float* __restrict__ colproj,
    const float* __restrict__ qrp, const int* __restrict__ quid,
    const float* __restrict__ krp, const int* __restrict__ kuid,
    const float* __restrict__ w1, const float* __restrict__ w2, const float* __restrict__ w3,
    const float* __restrict__ wpo, const float* __restrict__ wpd, const float* __restrict__ wpv,
    const float* __restrict__ wb,
    float* __restrict__ out_pair, u16* __restrict__ bias_ws)
{
  __shared__ float xp[2][16*33];     // 528 floats per wave
  int tid = threadIdx.x;
  int w   = tid >> 6;
  int l   = tid & 63;
  int lo  = l & 31;        // point lane (A/prologue) / out-channel col (B/D)
  int hi  = l >> 5;        // k-half of the fragment
  int ch0 = hi * 8;
  int s   = blockIdx.x >> 2;
  int qg  = blockIdx.x & 3;
  float* X = xp[w];

  // loop-invariant channel tables (8 channels per half-wave)
  float wox[8], woy[8], woz[8], wdd[8], wvv[8];
  *(float4*)&wox[0] = *(const float4*)&wpo[ch0];      *(float4*)&wox[4] = *(const float4*)&wpo[ch0+4];
  *(float4*)&woy[0] = *(const float4*)&wpo[16+ch0];   *(float4*)&woy[4] = *(const float4*)&wpo[16+ch0+4];
  *(float4*)&woz[0] = *(const float4*)&wpo[32+ch0];   *(float4*)&woz[4] = *(const float4*)&wpo[32+ch0+4];
  *(float4*)&wdd[0] = *(const float4*)&wpd[ch0];      *(float4*)&wdd[4] = *(const float4*)&wpd[ch0+4];
  *(float4*)&wvv[0] = *(const float4*)&wpv[ch0];      *(float4*)&wvv[4] = *(const float4*)&wpv[ch0+4];

  // B-fragments: lane holds W[k=ch0+j][col=lo] (bf16), zero for padded cols >=16
  bf16x8 B1, B2, B3;
  #pragma unroll
  for (int j = 0; j < 8; ++j){ B1[j] = 0; B2[j] = 0; B3[j] = 0; }
  if (lo < 16){
    #pragma unroll
    for (int j = 0; j < 8; ++j){
      B1[j] = (short)f2b(w1[(ch0+j)*16 + lo]);
      B2[j] = (short)f2b(w2[(ch0+j)*16 + lo]);
      B3[j] = (short)f2b(w3[(ch0+j)*16 + lo]);
    }
  }
  f32x16 Z;
  #pragma unroll
  for (int i = 0; i < 16; ++i) Z[i] = 0.f;

  #pragma unroll 1
  for (int q4 = 0; q4 < 4; ++q4){
    int q  = qg*8 + w*4 + q4;
    int sq = s*Q_ + q;
    float qx = qrp[sq*3+0], qy = qrp[sq*3+1], qz = qrp[sq*3+2];
    int   qu = quid[sq];
    float rp[8];
    *(float4*)&rp[0] = *(const float4*)&rowproj[(size_t)sq*CP_ + ch0];
    *(float4*)&rp[4] = *(const float4*)&rowproj[(size_t)sq*CP_ + ch0 + 4];

    #pragma unroll 1
    for (int kb = 0; kb < 4; ++kb){
      int k  = kb*32 + lo;
      int sk = s*K_ + k;
      int j  = q2k[sk];
      float kx = krp[sk*3+0], ky = krp[sk*3+1], kz = krp[sk*3+2];
      int   ku = kuid[sk];
      float cp[8];
      *(float4*)&cp[0] = *(const float4*)&colproj[(size_t)j*CP_ + ch0];
      *(float4*)&cp[4] = *(const float4*)&colproj[(size_t)j*CP_ + ch0 + 4];

      float ox = qx - kx, oy = qy - ky, oz = qz - kz;
      float vf = (qu == ku) ? 1.f : 0.f;
      float invd = vf / (1.f + ox*ox + oy*oy + oz*oz);

      float p[8];
      #pragma unroll
      for (int jj = 0; jj < 8; ++jj)
        p[jj] = rp[jj] + cp[jj]
              + vf*(ox*wox[jj] + oy*woy[jj] + oz*woz[jj])
              + invd*wdd[jj] + vf*wvv[jj];

      // ---- L1 ----
      bf16x8 a;
      #pragma unroll
      for (int jj = 0; jj < 8; ++jj) a[jj] = (short)f2b(fmaxf(p[jj], 0.f));
      f32x16 d = __builtin_amdgcn_mfma_f32_32x32x16_bf16(a, B1, Z, 0, 0, 0);

      // D (lane=out-channel col, regs=points) -> X[ch*33 + point]
      if (lo < 16){
        float* row = &X[lo*33 + 4*hi];
        *(float4*)&row[ 0] = make_float4(d[0],  d[1],  d[2],  d[3]);
        *(float4*)&row[ 8] = make_float4(d[4],  d[5],  d[6],  d[7]);
        *(float4*)&row[16] = make_float4(d[8],  d[9],  d[10], d[11]);
        *(float4*)&row[24] = make_float4(d[12], d[13], d[14], d[15]);
      }
      wave_fence();
      float yv[8];
      #pragma unroll
      for (int jj = 0; jj < 8; ++jj) yv[jj] = X[(ch0+jj)*33 + lo];
      wave_fence();

      // ---- L2 ----
      #pragma unroll
      for (int jj = 0; jj < 8; ++jj) a[jj] = (short)f2b(fmaxf(yv[jj], 0.f));
      d = __builtin_amdgcn_mfma_f32_32x32x16_bf16(a, B2, Z, 0, 0, 0);
      if (lo < 16){
        float* row = &X[lo*33 + 4*hi];
        *(float4*)&row[ 0] = make_float4(d[0],  d[1],  d[2],  d[3]);
        *(float4*)&row[ 8] = make_float4(d[4],  d[5],  d[6],  d[7]);
        *(float4*)&row[16] = make_float4(d[8],  d[9],  d[10], d[11]);
        *(float4*)&row[24] = make_float4(d[12], d[13], d[14], d[15]);
      }
      wave_fence();
      #pragma unroll
      for (int jj = 0; jj < 8; ++jj) yv[jj] = X[(ch0+jj)*33 + lo];
      wave_fence();

      // ---- L3 ----
      #pragma unroll
      for (int jj = 0; jj < 8; ++jj) a[jj] = (short)f2b(fmaxf(yv[jj], 0.f));
      d = __builtin_amdgcn_mfma_f32_32x32x16_bf16(a, B3, Z, 0, 0, 0);
      if (lo < 16){
        float* row = &X[lo*33 + 4*hi];
        *(float4*)&row[ 0] = make_float4(d[0],  d[1],  d[2],  d[3]);
        *(float4*)&row[ 8] = make_float4(d[4],  d[5],  d[6],  d[7]);
        *(float4*)&row[16] = make_float4(d[8],  d[9],  d[10], d[11]);
        *(float4*)&row[24] = make_float4(d[12], d[13], d[14], d[15]);
      }
      wave_fence();
      float pout[8];
      #pragma unroll
      for (int jj = 0; jj < 8; ++jj) pout[jj] = p[jj] + X[(ch0+jj)*33 + lo];
      wave_fence();

      // store out_pair (residual + MLP), 32B per lane
      size_t ob = ((size_t)sq*K_ + k)*CP_ + ch0;
      *(float4*)&out_pair[ob]     = make_float4(pout[0], pout[1], pout[2], pout[3]);
      *(float4*)&out_pair[ob + 4] = make_float4(pout[4], pout[5], pout[6], pout[7]);

      // bias: b[h] = sum_c pout[c]*wb[c][h]; combine channel halves via shfl
      float b0 = 0.f, b1 = 0.f, b2 = 0.f, b3 = 0.f;
      #pragma unroll
      for (int jj = 0; jj < 8; ++jj){
        float4 wv4 = *(const float4*)&wb[(ch0+jj)*4];
        float pj = pout[jj];
        b0 += pj*wv4.x; b1 += pj*wv4.y; b2 += pj*wv4.z; b3 += pj*wv4.w;
      }
      b0 += __shfl_xor(b0, 32, 64);
      b1 += __shfl_xor(b1, 32, 64);
      b2 += __shfl_xor(b2, 32, 64);
      b3 += __shfl_xor(b3, 32, 64);
      if (hi == 0){
        size_t bb = (((size_t)s*H_ + 0)*Q_ + q)*K_ + k;
        bias_ws[bb]             = f2b(b0);
        bias_ws[bb + Q_*K_]     = f2b(b1);
        bias_ws[bb + 2*Q_*K_]   = f2b(b2);
        bias_ws[bb + 3*Q_*K_]   = f2b(b3);
      }
    }
  }
}

// ---- N6: attention. One 128-thread block per (s,h). K/V staged in LDS (pitch 36). ----
__global__ __launch_bounds__(128) void n_attn(
    const float* __restrict__ Qp, const float* __restrict__ Kp, const float* __restrict__ Vp,
    const float* __restrict__ qmask, const u16* __restrict__ bias_ws, const int* __restrict__ q2k,
    float* __restrict__ O)
{
  __shared__ float Ks[128*36];
  __shared__ float Vs[128*36];
  __shared__ float msk[128];
  __shared__ float redm[64];
  __shared__ float reds[64];
  __shared__ float Osm[32*33];

  int b = blockIdx.x;
  int s = b >> 2, h = b & 3;
  int sq0 = s * Q_;
  int base = s * K_;
  int t = threadIdx.x;

  {
    int e = t & 7, rr = t >> 3;
    #pragma unroll
    for (int it = 0; it < 8; ++it){
      int row = it*16 + rr;
      int j = q2k[base + row];
      const float4* ksrc = (const float4*)&Kp[(size_t)j*CA_ + h*DH_];
      const float4* vsrc = (const float4*)&Vp[(size_t)j*CA_ + h*DH_];
      *(float4*)&Ks[row*36 + e*4] = ksrc[e];
      *(float4*)&Vs[row*36 + e*4] = vsrc[e];
    }
    int j0 = q2k[base + t];
    msk[t] = qmask[j0];
  }

  int q  = t & 31;
  int kr = t >> 5;
  float qreg[32];
  {
    const float4* qsrc = (const float4*)&Qp[(size_t)(sq0+q)*CA_ + h*DH_];
    #pragma unroll
    for (int d4 = 0; d4 < 8; ++d4){
      float4 v = qsrc[d4];
      qreg[d4*4+0] = v.x; qreg[d4*4+1] = v.y; qreg[d4*4+2] = v.z; qreg[d4*4+3] = v.w;
    }
  }

  u32 bw[16];
  {
    const uint4* bsrc = (const uint4*)&bias_ws[(((size_t)s*H_ + h)*Q_ + q)*K_ + kr*32];
    uint4 B;
    B = bsrc[0]; bw[0]=B.x;  bw[1]=B.y;  bw[2]=B.z;  bw[3]=B.w;
    B = bsrc[1]; bw[4]=B.x;  bw[5]=B.y;  bw[6]=B.z;  bw[7]=B.w;
    B = bsrc[2]; bw[8]=B.x;  bw[9]=B.y;  bw[10]=B.z; bw[11]=B.w;
    B = bsrc[3]; bw[12]=B.x; bw[13]=B.y; bw[14]=B.z; bw[15]=B.w;
  }
  __syncthreads();

  float p[32];
  #pragma unroll
  for (int kk = 0; kk < 32; ++kk){
    int k = kr*32 + kk;
    const float* kbase = &Ks[k*36];
    float acc = 0.f;
    #pragma unroll
    for (int d4 = 0; d4 < 8; ++d4){
      float4 kv = *(const float4*)(kbase + d4*4);
      acc += qreg[d4*4+0]*kv.x + qreg[d4*4+1]*kv.y + qreg[d4*4+2]*kv.z + qreg[d4*4+3]*kv.w;
    }
    float bz = b2f((u16)((bw[kk>>1] >> ((kk&1)*16)) & 0xffffu));
    p[kk] = (msk[k] > 0.f) ? (acc + bz) : -1e9f;
  }

  float m = p[0];
  #pragma unroll
  for (int kk = 1; kk < 32; ++kk) m = fmaxf(m, p[kk]);
  m = fmaxf(m, __shfl_xor(m, 32, 64));
  int wv = t >> 6;
  if ((t & 63) < 32) redm[wv*32 + q] = m;
  __syncthreads();
  float M = fmaxf(redm[q], redm[32 + q]);

  float sm = 0.f;
  #pragma unroll
  for (int kk = 0; kk < 32; ++kk){ p[kk] = __expf(p[kk] - M); sm += p[kk]; }
  sm += __shfl_xor(sm, 32, 64);
  if ((t & 63) < 32) reds[wv*32 + q] = sm;
  __syncthreads();
  float inv = 1.f / (reds[q] + reds[32 + q]);

  float acc[32];
  #pragma unroll
  for (int d = 0; d < 32; ++d) acc[d] = 0.f;
  #pragma unroll
  for (int kk = 0; kk < 32; ++kk){
    float w = p[kk];
    const float* vbase = &Vs[(kr*32 + kk)*36];
    #pragma unroll
    for (int d4 = 0; d4 < 8; ++d4){
      float4 vv = *(const float4*)(vbase + d4*4);
      acc[d4*4+0] += w*vv.x; acc[d4*4+1] += w*vv.y; acc[d4*4+2] += w*vv.z; acc[d4*4+3] += w*vv.w;
    }
  }
  #pragma unroll
  for (int d = 0; d < 32; ++d) acc[d] += __shfl_xor(acc[d], 32, 64);
  if (t < 32){
    #pragma unroll
    for (int d = 0; d < 32; ++d) Osm[q*33 + d] = acc[d];
  }
  __syncthreads();
  if (t >= 64 && t < 96){
    #pragma unroll
    for (int d = 0; d < 32; ++d) Osm[q*33 + d] = (Osm[q*33 + d] + acc[d]) * inv;
  }
  __syncthreads();

  #pragma unroll
  for (int it = 0; it < 2; ++it){
    int idx = it*128 + t;
    int qq = idx >> 3, e = idx & 7;
    float4 v = make_float4(Osm[qq*33 + e*4 + 0], Osm[qq*33 + e*4 + 1],
                           Osm[qq*33 + e*4 + 2], Osm[qq*33 + e*4 + 3]);
    *(float4*)&O[(size_t)(sq0+qq)*CA_ + h*DH_ + e*4] = v;
  }
}

// ---- N7: queries_act = (qsc + O @ wo) * qmask ----
__global__ __launch_bounds__(128) void n_qact(
    const float* __restrict__ qsc, const float* __restrict__ O, const float* __restrict__ qmask,
    const float* __restrict__ wo, float* __restrict__ qact, float* __restrict__ out_skip)
{
  int c = threadIdx.x;
  size_t r0 = (size_t)blockIdx.x * 16;
  float acc[16];
  #pragma unroll
  for (int r = 0; r < 16; ++r) acc[r] = 0.f;
  #pragma unroll 4
  for (int i = 0; i < CA_; ++i){
    float w = wo[i*CA_+c];
    #pragma unroll
    for (int r = 0; r < 16; ++r) acc[r] += O[(r0+r)*CA_+i] * w;
  }
  #pragma unroll
  for (int r = 0; r < 16; ++r){
    float v = (qsc[(r0+r)*CA_+c] + acc[r]) * qmask[r0+r];
    qact[(r0+r)*CA_+c] = v;
    out_skip[(r0+r)*CA_+c] = v;
  }
}

// ---- N8: proj + gather + masked mean ----
__global__ __launch_bounds__(384) void n_tok(
    const float* __restrict__ qact, const int* __restrict__ q2t, const float* __restrict__ amask,
    const float* __restrict__ wp, float* __restrict__ out_tok)
{
  int t = blockIdx.x, ct = threadIdx.x;
  int jd[D_];
  float mk[D_];
  #pragma unroll
  for (int d = 0; d < D_; ++d){
    jd[d] = q2t[t*D_ + d];
    mk[d] = amask[t*D_ + d];
  }
  float acc[D_];
  #pragma unroll
  for (int d = 0; d < D_; ++d) acc[d] = 0.f;
  #pragma unroll 4
  for (int i = 0; i < CA_; ++i){
    float w = wp[i*CT_ + ct];
    #pragma unroll
    for (int d = 0; d < D_; ++d) acc[d] += qact[(size_t)jd[d]*CA_ + i] * w;
  }
  float num = 0.f, den = 1e-10f;
  #pragma unroll
  for (int d = 0; d < D_; ++d){
    num += mk[d] * fmaxf(acc[d], 0.f);
    den += mk[d];
  }
  out_tok[(size_t)t*CT_ + ct] = num/den;
}

extern "C" void kernel_launch(void* const* d_in, const int* in_sizes, int n_in,
                              void* d_out, int out_size, void* d_ws, size_t ws_size,
                              hipStream_t stream) {
  (void)in_sizes; (void)n_in; (void)out_size; (void)ws_size;
  const float* ref_positions = (const float*)d_in[0];
  const float* ref_mask      = (const float*)d_in[1];
  const float* ref_charge    = (const float*)d_in[2];
  const float* atom_mask     = (const float*)d_in[3];
  const int*   ref_element   = (const int*)d_in[4];
  const int*   ref_chars     = (const int*)d_in[5];
  const int*   ref_uid       = (const int*)d_in[6];
  const int*   t2q           = (const int*)d_in[7];
  const int*   q2k           = (const int*)d_in[8];
  const int*   q2t           = (const int*)d_in[9];
  const float* w_ref_pos     = (const float*)d_in[10];
  const float* w_ref_mask    = (const float*)d_in[11];
  const float* w_ref_element = (const float*)d_in[12];
  const float* w_ref_charge  = (const float*)d_in[13];
  const float* w_ref_name    = (const float*)d_in[14];
  const float* w_s2p_row1    = (const float*)d_in[15];
  const float* w_s2p_col1    = (const float*)d_in[16];
  const float* w_pair_off1   = (const float*)d_in[17];
  const float* w_pair_dist1  = (const float*)d_in[18];
  const float* w_pair_valid  = (const float*)d_in[19];
  const float* w_mlp1        = (const float*)d_in[20];
  const float* w_mlp2        = (const float*)d_in[21];
  const float* w_mlp3        = (const float*)d_in[22];
  const float* wq            = (const float*)d_in[23];
  const float* wk            = (const float*)d_in[24];
  const float* wv            = (const float*)d_in[25];
  const float* wb            = (const float*)d_in[26];
  const float* wo            = (const float*)d_in[27];
  const float* w_proj        = (const float*)d_in[28];

  char* ws = (char*)d_ws;
  float* qsc     = (float*)(ws + 0);
  float* qmask   = (float*)(ws + 9437184);
  float* qrp     = (float*)(ws + 9732096);
  int*   quid    = (int*)  (ws + 9953280);
  float* krp     = (float*)(ws + 10027008);
  int*   kuid    = (int*)  (ws + 10911744);
  float* rowproj = (float*)(ws + 11206656);
  float* colproj = (float*)(ws + 12386304);
  float* Qp      = (float*)(ws + 13565952);
  float* Kp      = (float*)(ws + 23003136);
  float* Vp      = (float*)(ws + 32440320);
  float* O       = (float*)(ws + 41877504);
  float* qact    = (float*)(ws + 51314688);
  u16*   biasws  = (u16*)  (ws + 60751872);

  float* out = (float*)d_out;
  float* out_tok   = out + 0;
  float* out_skip  = out + 294912;
  float* out_qmask = out + 2654208;
  float* out_qsc   = out + 2672640;
  float* out_kmask = out + 5031936;
  float* out_ksc   = out + 5105664;
  float* out_pair  = out + 14542848;

  hipLaunchKernelGGL(n_qsc, dim3(SQ_), dim3(128), 0, stream,
      ref_positions, ref_mask, ref_charge, atom_mask, ref_element, ref_chars, ref_uid, t2q,
      w_ref_pos, w_ref_mask, w_ref_element, w_ref_charge, w_ref_name,
      qsc, qmask, qrp, quid, out_qsc, out_qmask);
  hipLaunchKernelGGL(n_keys, dim3(SK_/4), dim3(128), 0, stream,
      qsc, qmask, qrp, ref_uid, q2k, krp, kuid, out_ksc, out_kmask);
  hipLaunchKernelGGL(n_qkv, dim3(SQ_/16), dim3(128), 0, stream,
      qsc, wq, wk, wv, Qp, Kp, Vp);
  hipLaunchKernelGGL(n_proj16b, dim3(SQ_/4), dim3(128), 0, stream,
      qsc, w_s2p_row1, w_s2p_col1, rowproj, colproj);
  hipLaunchKernelGGL(n_pair, dim3(S_*4), dim3(128), 0, stream,
      q2k, rowproj, colproj, qrp, quid, krp, kuid,
      w_mlp1, w_mlp2, w_mlp3, w_pair_off1, w_pair_dist1, w_pair_valid, wb,
      out_pair, biasws);
  hipLaunchKernelGGL(n_attn, dim3(S_*H_), dim3(128), 0, stream,
      Qp, Kp, Vp, qmask, biasws, q2k, O);
  hipLaunchKernelGGL(n_qact, dim3(SQ_/16), dim3(128), 0, stream,
      qsc, O, qmask, wo, qact, out_skip);
  hipLaunchKernelGGL(n_tok, dim3(T_), dim3(384), 0, stream,
      qact, q2t, atom_mask, w_proj, out_tok);
}

// Round 9
// 535.244 us; speedup vs baseline: 1.1820x; 1.0508x over previous
//
#include <hip/hip_runtime.h>

typedef unsigned short u16;
typedef unsigned int u32;
typedef short bf16x8 __attribute__((ext_vector_type(8)));
typedef float f32x16 __attribute__((ext_vector_type(16)));

#define T_ 768
#define D_ 24
#define S_ 576
#define Q_ 32
#define K_ 128
#define CA_ 128
#define CP_ 16
#define CT_ 384
#define H_ 4
#define DH_ 32
#define SQ_ (S_*Q_)
#define SK_ (S_*K_)

__device__ __forceinline__ float b2f(u16 u){ return __uint_as_float(((u32)u)<<16); }
__device__ __forceinline__ u16 f2b(float f){ u32 x=__float_as_uint(f); return (u16)((x + 0x7fffu + ((x>>16)&1u))>>16); }

// ---- N1: per-atom conditioning gathered to query slots; also qrp/quid ----
__global__ __launch_bounds__(128) void n_qsc(
    const float* __restrict__ pos, const float* __restrict__ rmask, const float* __restrict__ charge,
    const float* __restrict__ amask, const int* __restrict__ elem, const int* __restrict__ chars,
    const int* __restrict__ uid, const int* __restrict__ t2q,
    const float* __restrict__ w_pos, const float* __restrict__ w_mask, const float* __restrict__ w_elem,
    const float* __restrict__ w_chg, const float* __restrict__ w_name,
    float* __restrict__ qsc, float* __restrict__ qmask, float* __restrict__ qrp, int* __restrict__ quid,
    float* __restrict__ out_qsc, float* __restrict__ out_qmask)
{
  int slot = blockIdx.x, ch = threadIdx.x;
  int a = t2q[slot];
  float p0 = pos[a*3+0], p1 = pos[a*3+1], p2 = pos[a*3+2];
  float m  = rmask[a];
  float cg = asinhf(charge[a]);
  int e  = elem[a];
  int c0 = chars[a*4+0], c1 = chars[a*4+1], c2 = chars[a*4+2], c3 = chars[a*4+3];
  float v = p0*w_pos[0*CA_+ch] + p1*w_pos[1*CA_+ch] + p2*w_pos[2*CA_+ch];
  v += m * w_mask[ch];
  v += w_elem[e*CA_+ch];
  v += cg * w_chg[ch];
  v += w_name[(0*64+c0)*CA_+ch] + w_name[(1*64+c1)*CA_+ch]
     + w_name[(2*64+c2)*CA_+ch] + w_name[(3*64+c3)*CA_+ch];
  v *= m;
  qsc[(size_t)slot*CA_+ch] = v;
  out_qsc[(size_t)slot*CA_+ch] = v;
  if (ch < 3) qrp[slot*3+ch] = pos[a*3+ch];
  if (ch == 0){
    float am = amask[a];
    qmask[slot] = am;
    out_qmask[slot] = am;
    quid[slot] = uid[a];
  }
}

// ---- N2: key-space gathers. 4 rows/block, one float4 per thread ----
__global__ __launch_bounds__(128) void n_keys(
    const float* __restrict__ qsc, const float* __restrict__ qmask, const float* __restrict__ qrp,
    const int* __restrict__ uid, const int* __restrict__ q2k,
    float* __restrict__ krp, int* __restrict__ kuid,
    float* __restrict__ out_ksc, float* __restrict__ out_kmask)
{
  int r = threadIdx.x >> 5;
  int e = threadIdx.x & 31;
  int sk = blockIdx.x*4 + r;
  int j = q2k[sk];
  *(float4*)&out_ksc[(size_t)sk*CA_ + e*4] = *(const float4*)&qsc[(size_t)j*CA_ + e*4];
  if (e < 3) krp[sk*3+e] = qrp[j*3+e];
  if (e == 0){
    out_kmask[sk] = qmask[j];
    kuid[sk] = uid[j];
  }
}

// ---- N3: fused QKV projection ----
__global__ __launch_bounds__(128) void n_qkv(
    const float* __restrict__ X, const float* __restrict__ wq, const float* __restrict__ wk,
    const float* __restrict__ wv, float* __restrict__ Qp, float* __restrict__ Kp, float* __restrict__ Vp)
{
  int c = threadIdx.x;
  size_t r0 = (size_t)blockIdx.x * 16;
  float aq[16], ak[16], av[16];
  #pragma unroll
  for (int r = 0; r < 16; ++r){ aq[r] = 0.f; ak[r] = 0.f; av[r] = 0.f; }
  #pragma unroll 4
  for (int i = 0; i < CA_; ++i){
    float q = wq[i*CA_+c];
    float k = wk[i*CA_+c];
    float v = wv[i*CA_+c];
    #pragma unroll
    for (int r = 0; r < 16; ++r){
      float x = X[(r0+r)*CA_ + i];
      aq[r] += x * q;
      ak[r] += x * k;
      av[r] += x * v;
    }
  }
  #pragma unroll
  for (int r = 0; r < 16; ++r){
    Qp[(r0+r)*CA_+c] = aq[r] * 0.17677669529663687f;
    Kp[(r0+r)*CA_+c] = ak[r];
    Vp[(r0+r)*CA_+c] = av[r];
  }
}

// ---- N4: fused row+col 128->16 relu-linear ----
__global__ __launch_bounds__(128) void n_proj16b(
    const float* __restrict__ X, const float* __restrict__ Wr, const float* __restrict__ Wc,
    float* __restrict__ Yr, float* __restrict__ Yc)
{
  int row = blockIdx.x*4 + (threadIdx.x >> 5);
  int c = threadIdx.x & 31;
  const float* W = (c < 16) ? Wr : Wc;
  float* Y = (c < 16) ? Yr : Yc;
  int cc = c & 15;
  float acc = 0.f;
  for (int i = 0; i < CA_; ++i)
    acc += fmaxf(X[(size_t)row*CA_+i], 0.f) * W[i*CP_+cc];
  Y[(size_t)row*CP_+cc] = acc;
}

// ---- N5: pair conditioning + MLP via bf16 MFMA, transposed-operand form.
//      Each layer computes Y^T = W^T x Y^T: A = W^T (lane=out-ch row, loaded once),
//      B = data (lane=point, regs=k) -> D keeps lane=point. Inter-layer fixup is a
//      lane^32 exchange (8 shfl_xor) instead of an LDS round-trip: per the verified
//      D row map (r&3)+8*(r>>2)+4*hi, hi=0 holds rows 0-3/8-11..., hi=1 rows 4-7/12-15...
//      -> B_next[j<4] = hi ? partner d[j+4] : own d[j]; [j>=4] = hi ? own d[j] : partner d[j-4].
//      Zero LDS, zero fences, no divergent stores. Bit-identical math to the r7 version. ----
__global__ __launch_bounds__(128) void n_pair(
    const int* __restrict__ q2k, const float* __restrict__ rowproj, const float* __restrict__ colproj,
    const float* __restrict__ qrp, const int* __restrict__ quid,
    const float* __restrict__ krp, const int* __restrict__ kuid,
    const float* __restrict__ w1, const float* __restrict__ w2, const float* __restrict__ w3,
    const float* __restrict__ wpo, const float* __restrict__ wpd, const float* __restrict__ wpv,
    const float* __restrict__ wb,
    float* __restrict__ out_pair, u16* __restrict__ bias_ws)
{
  int tid = threadIdx.x;
  int w   = tid >> 6;
  int l   = tid & 63;
  int lo  = l & 31;        // point lane (B col / D col); weight row for A
  int hi  = l >> 5;        // k-half of the fragment
  int ch0 = hi * 8;
  int s   = blockIdx.x >> 2;
  int qg  = blockIdx.x & 3;

  // loop-invariant channel tables (8 channels per half-wave)
  float wox[8], woy[8], woz[8], wdd[8], wvv[8];
  *(float4*)&wox[0] = *(const float4*)&wpo[ch0];      *(float4*)&wox[4] = *(const float4*)&wpo[ch0+4];
  *(float4*)&woy[0] = *(const float4*)&wpo[16+ch0];   *(float4*)&woy[4] = *(const float4*)&wpo[16+ch0+4];
  *(float4*)&woz[0] = *(const float4*)&wpo[32+ch0];   *(float4*)&woz[4] = *(const float4*)&wpo[32+ch0+4];
  *(float4*)&wdd[0] = *(const float4*)&wpd[ch0];      *(float4*)&wdd[4] = *(const float4*)&wpd[ch0+4];
  *(float4*)&wvv[0] = *(const float4*)&wpv[ch0];      *(float4*)&wvv[4] = *(const float4*)&wpv[ch0+4];

  // A-fragments = W^T: A[m=lo][k=ch0+j] = W[ch0+j][lo]; zero rows m>=16.
  bf16x8 A1, A2, A3;
  #pragma unroll
  for (int j = 0; j < 8; ++j){ A1[j] = 0; A2[j] = 0; A3[j] = 0; }
  if (lo < 16){
    #pragma unroll
    for (int j = 0; j < 8; ++j){
      A1[j] = (short)f2b(w1[(ch0+j)*16 + lo]);
      A2[j] = (short)f2b(w2[(ch0+j)*16 + lo]);
      A3[j] = (short)f2b(w3[(ch0+j)*16 + lo]);
    }
  }
  f32x16 Z;
  #pragma unroll
  for (int i = 0; i < 16; ++i) Z[i] = 0.f;

  #pragma unroll 1
  for (int q4 = 0; q4 < 4; ++q4){
    int q  = qg*8 + w*4 + q4;
    int sq = s*Q_ + q;
    float qx = qrp[sq*3+0], qy = qrp[sq*3+1], qz = qrp[sq*3+2];
    int   qu = quid[sq];
    float rp[8];
    *(float4*)&rp[0] = *(const float4*)&rowproj[(size_t)sq*CP_ + ch0];
    *(float4*)&rp[4] = *(const float4*)&rowproj[(size_t)sq*CP_ + ch0 + 4];

    #pragma unroll 1
    for (int kb = 0; kb < 4; ++kb){
      int k  = kb*32 + lo;
      int sk = s*K_ + k;
      int j  = q2k[sk];
      float kx = krp[sk*3+0], ky = krp[sk*3+1], kz = krp[sk*3+2];
      int   ku = kuid[sk];
      float cp[8];
      *(float4*)&cp[0] = *(const float4*)&colproj[(size_t)j*CP_ + ch0];
      *(float4*)&cp[4] = *(const float4*)&colproj[(size_t)j*CP_ + ch0 + 4];

      float ox = qx - kx, oy = qy - ky, oz = qz - kz;
      float vf = (qu == ku) ? 1.f : 0.f;
      float invd = vf / (1.f + ox*ox + oy*oy + oz*oz);

      float p[8];
      #pragma unroll
      for (int jj = 0; jj < 8; ++jj)
        p[jj] = rp[jj] + cp[jj]
              + vf*(ox*wox[jj] + oy*woy[jj] + oz*woz[jj])
              + invd*wdd[jj] + vf*wvv[jj];

      // ---- L1: B = relu(p) (lane=point, k=ch0+j) ----
      bf16x8 bfr;
      #pragma unroll
      for (int jj = 0; jj < 8; ++jj) bfr[jj] = (short)f2b(fmaxf(p[jj], 0.f));
      f32x16 d = __builtin_amdgcn_mfma_f32_32x32x16_bf16(A1, bfr, Z, 0, 0, 0);

      // lane^32 exchange -> next B fragment (rows 0..15 of D)
      float t[8];
      #pragma unroll
      for (int r = 0; r < 8; ++r) t[r] = __shfl_xor(d[r], 32, 64);
      #pragma unroll
      for (int jj = 0; jj < 4; ++jj){
        float v0 = hi ? t[jj+4] : d[jj];
        float v1 = hi ? d[jj+4] : t[jj];
        bfr[jj]   = (short)f2b(fmaxf(v0, 0.f));
        bfr[jj+4] = (short)f2b(fmaxf(v1, 0.f));
      }
      // ---- L2 ----
      d = __builtin_amdgcn_mfma_f32_32x32x16_bf16(A2, bfr, Z, 0, 0, 0);
      #pragma unroll
      for (int r = 0; r < 8; ++r) t[r] = __shfl_xor(d[r], 32, 64);
      #pragma unroll
      for (int jj = 0; jj < 4; ++jj){
        float v0 = hi ? t[jj+4] : d[jj];
        float v1 = hi ? d[jj+4] : t[jj];
        bfr[jj]   = (short)f2b(fmaxf(v0, 0.f));
        bfr[jj+4] = (short)f2b(fmaxf(v1, 0.f));
      }
      // ---- L3 ----
      d = __builtin_amdgcn_mfma_f32_32x32x16_bf16(A3, bfr, Z, 0, 0, 0);
      #pragma unroll
      for (int r = 0; r < 8; ++r) t[r] = __shfl_xor(d[r], 32, 64);
      float pout[8];
      #pragma unroll
      for (int jj = 0; jj < 4; ++jj){
        pout[jj]   = p[jj]   + (hi ? t[jj+4] : d[jj]);
        pout[jj+4] = p[jj+4] + (hi ? d[jj+4] : t[jj]);
      }

      // store out_pair (residual + MLP), 32B per lane
      size_t ob = ((size_t)sq*K_ + k)*CP_ + ch0;
      *(float4*)&out_pair[ob]     = make_float4(pout[0], pout[1], pout[2], pout[3]);
      *(float4*)&out_pair[ob + 4] = make_float4(pout[4], pout[5], pout[6], pout[7]);

      // bias: b[h] = sum_c pout[c]*wb[c][h]; combine channel halves via shfl
      float b0 = 0.f, b1 = 0.f, b2 = 0.f, b3 = 0.f;
      #pragma unroll
      for (int jj = 0; jj < 8; ++jj){
        float4 wv4 = *(const float4*)&wb[(ch0+jj)*4];
        float pj = pout[jj];
        b0 += pj*wv4.x; b1 += pj*wv4.y; b2 += pj*wv4.z; b3 += pj*wv4.w;
      }
      b0 += __shfl_xor(b0, 32, 64);
      b1 += __shfl_xor(b1, 32, 64);
      b2 += __shfl_xor(b2, 32, 64);
      b3 += __shfl_xor(b3, 32, 64);
      if (hi == 0){
        size_t bb = (((size_t)s*H_ + 0)*Q_ + q)*K_ + k;
        bias_ws[bb]             = f2b(b0);
        bias_ws[bb + Q_*K_]     = f2b(b1);
        bias_ws[bb + 2*Q_*K_]   = f2b(b2);
        bias_ws[bb + 3*Q_*K_]   = f2b(b3);
      }
    }
  }
}

// ---- N6: attention. One 128-thread block per (s,h). K/V staged in LDS (pitch 36). ----
__global__ __launch_bounds__(128) void n_attn(
    const float* __restrict__ Qp, const float* __restrict__ Kp, const float* __restrict__ Vp,
    const float* __restrict__ qmask, const u16* __restrict__ bias_ws, const int* __restrict__ q2k,
    float* __restrict__ O)
{
  __shared__ float Ks[128*36];
  __shared__ float Vs[128*36];
  __shared__ float msk[128];
  __shared__ float redm[64];
  __shared__ float reds[64];
  __shared__ float Osm[32*33];

  int b = blockIdx.x;
  int s = b >> 2, h = b & 3;
  int sq0 = s * Q_;
  int base = s * K_;
  int t = threadIdx.x;

  {
    int e = t & 7, rr = t >> 3;
    #pragma unroll
    for (int it = 0; it < 8; ++it){
      int row = it*16 + rr;
      int j = q2k[base + row];
      const float4* ksrc = (const float4*)&Kp[(size_t)j*CA_ + h*DH_];
      const float4* vsrc = (const float4*)&Vp[(size_t)j*CA_ + h*DH_];
      *(float4*)&Ks[row*36 + e*4] = ksrc[e];
      *(float4*)&Vs[row*36 + e*4] = vsrc[e];
    }
    int j0 = q2k[base + t];
    msk[t] = qmask[j0];
  }

  int q  = t & 31;
  int kr = t >> 5;
  float qreg[32];
  {
    const float4* qsrc = (const float4*)&Qp[(size_t)(sq0+q)*CA_ + h*DH_];
    #pragma unroll
    for (int d4 = 0; d4 < 8; ++d4){
      float4 v = qsrc[d4];
      qreg[d4*4+0] = v.x; qreg[d4*4+1] = v.y; qreg[d4*4+2] = v.z; qreg[d4*4+3] = v.w;
    }
  }

  u32 bw[16];
  {
    const uint4* bsrc = (const uint4*)&bias_ws[(((size_t)s*H_ + h)*Q_ + q)*K_ + kr*32];
    uint4 B;
    B = bsrc[0]; bw[0]=B.x;  bw[1]=B.y;  bw[2]=B.z;  bw[3]=B.w;
    B = bsrc[1]; bw[4]=B.x;  bw[5]=B.y;  bw[6]=B.z;  bw[7]=B.w;
    B = bsrc[2]; bw[8]=B.x;  bw[9]=B.y;  bw[10]=B.z; bw[11]=B.w;
    B = bsrc[3]; bw[12]=B.x; bw[13]=B.y; bw[14]=B.z; bw[15]=B.w;
  }
  __syncthreads();

  float p[32];
  #pragma unroll
  for (int kk = 0; kk < 32; ++kk){
    int k = kr*32 + kk;
    const float* kbase = &Ks[k*36];
    float acc = 0.f;
    #pragma unroll
    for (int d4 = 0; d4 < 8; ++d4){
      float4 kv = *(const float4*)(kbase + d4*4);
      acc += qreg[d4*4+0]*kv.x + qreg[d4*4+1]*kv.y + qreg[d4*4+2]*kv.z + qreg[d4*4+3]*kv.w;
    }
    float bz = b2f((u16)((bw[kk>>1] >> ((kk&1)*16)) & 0xffffu));
    p[kk] = (msk[k] > 0.f) ? (acc + bz) : -1e9f;
  }

  float m = p[0];
  #pragma unroll
  for (int kk = 1; kk < 32; ++kk) m = fmaxf(m, p[kk]);
  m = fmaxf(m, __shfl_xor(m, 32, 64));
  int wv = t >> 6;
  if ((t & 63) < 32) redm[wv*32 + q] = m;
  __syncthreads();
  float M = fmaxf(redm[q], redm[32 + q]);

  float sm = 0.f;
  #pragma unroll
  for (int kk = 0; kk < 32; ++kk){ p[kk] = __expf(p[kk] - M); sm += p[kk]; }
  sm += __shfl_xor(sm, 32, 64);
  if ((t & 63) < 32) reds[wv*32 + q] = sm;
  __syncthreads();
  float inv = 1.f / (reds[q] + reds[32 + q]);

  float acc[32];
  #pragma unroll
  for (int d = 0; d < 32; ++d) acc[d] = 0.f;
  #pragma unroll
  for (int kk = 0; kk < 32; ++kk){
    float w = p[kk];
    const float* vbase = &Vs[(kr*32 + kk)*36];
    #pragma unroll
    for (int d4 = 0; d4 < 8; ++d4){
      float4 vv = *(const float4*)(vbase + d4*4);
      acc[d4*4+0] += w*vv.x; acc[d4*4+1] += w*vv.y; acc[d4*4+2] += w*vv.z; acc[d4*4+3] += w*vv.w;
    }
  }
  #pragma unroll
  for (int d = 0; d < 32; ++d) acc[d] += __shfl_xor(acc[d], 32, 64);
  if (t < 32){
    #pragma unroll
    for (int d = 0; d < 32; ++d) Osm[q*33 + d] = acc[d];
  }
  __syncthreads();
  if (t >= 64 && t < 96){
    #pragma unroll
    for (int d = 0; d < 32; ++d) Osm[q*33 + d] = (Osm[q*33 + d] + acc[d]) * inv;
  }
  __syncthreads();

  #pragma unroll
  for (int it = 0; it < 2; ++it){
    int idx = it*128 + t;
    int qq = idx >> 3, e = idx & 7;
    float4 v = make_float4(Osm[qq*33 + e*4 + 0], Osm[qq*33 + e*4 + 1],
                           Osm[qq*33 + e*4 + 2], Osm[qq*33 + e*4 + 3]);
    *(float4*)&O[(size_t)(sq0+qq)*CA_ + h*DH_ + e*4] = v;
  }
}

// ---- N7: queries_act = (qsc + O @ wo) * qmask ----
__global__ __launch_bounds__(128) void n_qact(
    const float* __restrict__ qsc, const float* __restrict__ O, const float* __restrict__ qmask,
    const float* __restrict__ wo, float* __restrict__ qact, float* __restrict__ out_skip)
{
  int c = threadIdx.x;
  size_t r0 = (size_t)blockIdx.x * 16;
  float acc[16];
  #pragma unroll
  for (int r = 0; r < 16; ++r) acc[r] = 0.f;
  #pragma unroll 4
  for (int i = 0; i < CA_; ++i){
    float w = wo[i*CA_+c];
    #pragma unroll
    for (int r = 0; r < 16; ++r) acc[r] += O[(r0+r)*CA_+i] * w;
  }
  #pragma unroll
  for (int r = 0; r < 16; ++r){
    float v = (qsc[(r0+r)*CA_+c] + acc[r]) * qmask[r0+r];
    qact[(r0+r)*CA_+c] = v;
    out_skip[(r0+r)*CA_+c] = v;
  }
}

// ---- N8: proj + gather + masked mean ----
__global__ __launch_bounds__(384) void n_tok(
    const float* __restrict__ qact, const int* __restrict__ q2t, const float* __restrict__ amask,
    const float* __restrict__ wp, float* __restrict__ out_tok)
{
  int t = blockIdx.x, ct = threadIdx.x;
  int jd[D_];
  float mk[D_];
  #pragma unroll
  for (int d = 0; d < D_; ++d){
    jd[d] = q2t[t*D_ + d];
    mk[d] = amask[t*D_ + d];
  }
  float acc[D_];
  #pragma unroll
  for (int d = 0; d < D_; ++d) acc[d] = 0.f;
  #pragma unroll 4
  for (int i = 0; i < CA_; ++i){
    float w = wp[i*CT_ + ct];
    #pragma unroll
    for (int d = 0; d < D_; ++d) acc[d] += qact[(size_t)jd[d]*CA_ + i] * w;
  }
  float num = 0.f, den = 1e-10f;
  #pragma unroll
  for (int d = 0; d < D_; ++d){
    num += mk[d] * fmaxf(acc[d], 0.f);
    den += mk[d];
  }
  out_tok[(size_t)t*CT_ + ct] = num/den;
}

extern "C" void kernel_launch(void* const* d_in, const int* in_sizes, int n_in,
                              void* d_out, int out_size, void* d_ws, size_t ws_size,
                              hipStream_t stream) {
  (void)in_sizes; (void)n_in; (void)out_size; (void)ws_size;
  const float* ref_positions = (const float*)d_in[0];
  const float* ref_mask      = (const float*)d_in[1];
  const float* ref_charge    = (const float*)d_in[2];
  const float* atom_mask     = (const float*)d_in[3];
  const int*   ref_element   = (const int*)d_in[4];
  const int*   ref_chars     = (const int*)d_in[5];
  const int*   ref_uid       = (const int*)d_in[6];
  const int*   t2q           = (const int*)d_in[7];
  const int*   q2k           = (const int*)d_in[8];
  const int*   q2t           = (const int*)d_in[9];
  const float* w_ref_pos     = (const float*)d_in[10];
  const float* w_ref_mask    = (const float*)d_in[11];
  const float* w_ref_element = (const float*)d_in[12];
  const float* w_ref_charge  = (const float*)d_in[13];
  const float* w_ref_name    = (const float*)d_in[14];
  const float* w_s2p_row1    = (const float*)d_in[15];
  const float* w_s2p_col1    = (const float*)d_in[16];
  const float* w_pair_off1   = (const float*)d_in[17];
  const float* w_pair_dist1  = (const float*)d_in[18];
  const float* w_pair_valid  = (const float*)d_in[19];
  const float* w_mlp1        = (const float*)d_in[20];
  const float* w_mlp2        = (const float*)d_in[21];
  const float* w_mlp3        = (const float*)d_in[22];
  const float* wq            = (const float*)d_in[23];
  const float* wk            = (const float*)d_in[24];
  const float* wv            = (const float*)d_in[25];
  const float* wb            = (const float*)d_in[26];
  const float* wo            = (const float*)d_in[27];
  const float* w_proj        = (const float*)d_in[28];

  char* ws = (char*)d_ws;
  float* qsc     = (float*)(ws + 0);
  float* qmask   = (float*)(ws + 9437184);
  float* qrp     = (float*)(ws + 9732096);
  int*   quid    = (int*)  (ws + 9953280);
  float* krp     = (float*)(ws + 10027008);
  int*   kuid    = (int*)  (ws + 10911744);
  float* rowproj = (float*)(ws + 11206656);
  float* colproj = (float*)(ws + 12386304);
  float* Qp      = (float*)(ws + 13565952);
  float* Kp      = (float*)(ws + 23003136);
  float* Vp      = (float*)(ws + 32440320);
  float* O       = (float*)(ws + 41877504);
  float* qact    = (float*)(ws + 51314688);
  u16*   biasws  = (u16*)  (ws + 60751872);

  float* out = (float*)d_out;
  float* out_tok   = out + 0;
  float* out_skip  = out + 294912;
  float* out_qmask = out + 2654208;
  float* out_qsc   = out + 2672640;
  float* out_kmask = out + 5031936;
  float* out_ksc   = out + 5105664;
  float* out_pair  = out + 14542848;

  hipLaunchKernelGGL(n_qsc, dim3(SQ_), dim3(128), 0, stream,
      ref_positions, ref_mask, ref_charge, atom_mask, ref_element, ref_chars, ref_uid, t2q,
      w_ref_pos, w_ref_mask, w_ref_element, w_ref_charge, w_ref_name,
      qsc, qmask, qrp, quid, out_qsc, out_qmask);
  hipLaunchKernelGGL(n_keys, dim3(SK_/4), dim3(128), 0, stream,
      qsc, qmask, qrp, ref_uid, q2k, krp, kuid, out_ksc, out_kmask);
  hipLaunchKernelGGL(n_qkv, dim3(SQ_/16), dim3(128), 0, stream,
      qsc, wq, wk, wv, Qp, Kp, Vp);
  hipLaunchKernelGGL(n_proj16b, dim3(SQ_/4), dim3(128), 0, stream,
      qsc, w_s2p_row1, w_s2p_col1, rowproj, colproj);
  hipLaunchKernelGGL(n_pair, dim3(S_*4), dim3(128), 0, stream,
      q2k, rowproj, colproj, qrp, quid, krp, kuid,
      w_mlp1, w_mlp2, w_mlp3, w_pair_off1, w_pair_dist1, w_pair_valid, wb,
      out_pair, biasws);
  hipLaunchKernelGGL(n_attn, dim3(S_*H_), dim3(128), 0, stream,
      Qp, Kp, Vp, qmask, biasws, q2k, O);
  hipLaunchKernelGGL(n_qact, dim3(SQ_/16), dim3(128), 0, stream,
      qsc, O, qmask, wo, qact, out_skip);
  hipLaunchKernelGGL(n_tok, dim3(T_), dim3(384), 0, stream,
      qact, q2t, atom_mask, w_proj, out_tok);
}

// Round 10
// 532.840 us; speedup vs baseline: 1.1874x; 1.0045x over previous
//
#include <hip/hip_runtime.h>

typedef unsigned short u16;
typedef unsigned int u32;
typedef short bf16x8 __attribute__((ext_vector_type(8)));
typedef float f32x16 __attribute__((ext_vector_type(16)));

#define T_ 768
#define D_ 24
#define S_ 576
#define Q_ 32
#define K_ 128
#define CA_ 128
#define CP_ 16
#define CT_ 384
#define H_ 4
#define DH_ 32
#define SQ_ (S_*Q_)
#define SK_ (S_*K_)

__device__ __forceinline__ float b2f(u16 u){ return __uint_as_float(((u32)u)<<16); }
__device__ __forceinline__ u16 f2b(float f){ u32 x=__float_as_uint(f); return (u16)((x + 0x7fffu + ((x>>16)&1u))>>16); }

// ---- N1: per-atom conditioning gathered to query slots (8 slots/block).
//      Writes ONLY the output copies (out_qsc/out_qmask) + small ws side arrays. ----
__global__ __launch_bounds__(128) void n_qsc(
    const float* __restrict__ pos, const float* __restrict__ rmask, const float* __restrict__ charge,
    const float* __restrict__ amask, const int* __restrict__ elem, const int* __restrict__ chars,
    const int* __restrict__ uid, const int* __restrict__ t2q,
    const float* __restrict__ w_pos, const float* __restrict__ w_mask, const float* __restrict__ w_elem,
    const float* __restrict__ w_chg, const float* __restrict__ w_name,
    float* __restrict__ qrp, int* __restrict__ quid,
    float* __restrict__ out_qsc, float* __restrict__ out_qmask)
{
  int ch = threadIdx.x;
  #pragma unroll 1
  for (int sl = 0; sl < 8; ++sl){
    int slot = blockIdx.x*8 + sl;
    int a = t2q[slot];                       // uniform -> s_load chain
    float p0 = pos[a*3+0], p1 = pos[a*3+1], p2 = pos[a*3+2];
    float m  = rmask[a];
    float cg = asinhf(charge[a]);
    int e  = elem[a];
    int c0 = chars[a*4+0], c1 = chars[a*4+1], c2 = chars[a*4+2], c3 = chars[a*4+3];
    float v = p0*w_pos[0*CA_+ch] + p1*w_pos[1*CA_+ch] + p2*w_pos[2*CA_+ch];
    v += m * w_mask[ch];
    v += w_elem[e*CA_+ch];
    v += cg * w_chg[ch];
    v += w_name[(0*64+c0)*CA_+ch] + w_name[(1*64+c1)*CA_+ch]
       + w_name[(2*64+c2)*CA_+ch] + w_name[(3*64+c3)*CA_+ch];
    v *= m;
    out_qsc[(size_t)slot*CA_+ch] = v;
    if (ch < 3) qrp[slot*3+ch] = pos[a*3+ch];
    if (ch == 0){
      out_qmask[slot] = amask[a];
      quid[slot] = uid[a];
    }
  }
}

// ---- N2: key-space gathers (pure copy now). 16 rows/block, one float4/thread/step ----
__global__ __launch_bounds__(128) void n_keys(
    const float* __restrict__ qsc, const float* __restrict__ qmask, const int* __restrict__ q2k,
    float* __restrict__ out_ksc, float* __restrict__ out_kmask)
{
  int e = threadIdx.x & 31;
  int rr = threadIdx.x >> 5;
  #pragma unroll
  for (int it = 0; it < 4; ++it){
    int sk = blockIdx.x*16 + it*4 + rr;
    int j = q2k[sk];
    *(float4*)&out_ksc[(size_t)sk*CA_ + e*4] = *(const float4*)&qsc[(size_t)j*CA_ + e*4];
    if (e == 0) out_kmask[sk] = qmask[j];
  }
}

// ---- N3: fused QKV projection ----
__global__ __launch_bounds__(128) void n_qkv(
    const float* __restrict__ X, const float* __restrict__ wq, const float* __restrict__ wk,
    const float* __restrict__ wv, float* __restrict__ Qp, float* __restrict__ Kp, float* __restrict__ Vp)
{
  int c = threadIdx.x;
  size_t r0 = (size_t)blockIdx.x * 16;
  float aq[16], ak[16], av[16];
  #pragma unroll
  for (int r = 0; r < 16; ++r){ aq[r] = 0.f; ak[r] = 0.f; av[r] = 0.f; }
  #pragma unroll 4
  for (int i = 0; i < CA_; ++i){
    float q = wq[i*CA_+c];
    float k = wk[i*CA_+c];
    float v = wv[i*CA_+c];
    #pragma unroll
    for (int r = 0; r < 16; ++r){
      float x = X[(r0+r)*CA_ + i];
      aq[r] += x * q;
      ak[r] += x * k;
      av[r] += x * v;
    }
  }
  #pragma unroll
  for (int r = 0; r < 16; ++r){
    Qp[(r0+r)*CA_+c] = aq[r] * 0.17677669529663687f;
    Kp[(r0+r)*CA_+c] = ak[r];
    Vp[(r0+r)*CA_+c] = av[r];
  }
}

// ---- N4: fused row+col 128->16 relu-linear ----
__global__ __launch_bounds__(128) void n_proj16b(
    const float* __restrict__ X, const float* __restrict__ Wr, const float* __restrict__ Wc,
    float* __restrict__ Yr, float* __restrict__ Yc)
{
  int row = blockIdx.x*4 + (threadIdx.x >> 5);
  int c = threadIdx.x & 31;
  const float* W = (c < 16) ? Wr : Wc;
  float* Y = (c < 16) ? Yr : Yc;
  int cc = c & 15;
  float acc = 0.f;
  for (int i = 0; i < CA_; ++i)
    acc += fmaxf(X[(size_t)row*CA_+i], 0.f) * W[i*CP_+cc];
  Y[(size_t)row*CP_+cc] = acc;
}

// ---- N5: pair conditioning + MLP via bf16 MFMA, transposed-operand form.
//      A = W^T (loaded once), B = data (lane=point) -> D stays lane=point; inter-layer
//      fixup = lane^32 shfl exchange (verified r9). Key-side operands read directly via
//      j = q2k[sk] (krp/kuid arrays eliminated; identical values). ----
__global__ __launch_bounds__(128) void n_pair(
    const int* __restrict__ q2k, const float* __restrict__ rowproj, const float* __restrict__ colproj,
    const float* __restrict__ qrp, const int* __restrict__ quid, const int* __restrict__ uid,
    const float* __restrict__ w1, const float* __restrict__ w2, const float* __restrict__ w3,
    const float* __restrict__ wpo, const float* __restrict__ wpd, const float* __restrict__ wpv,
    const float* __restrict__ wb,
    float* __restrict__ out_pair, u16* __restrict__ bias_ws)
{
  int tid = threadIdx.x;
  int w   = tid >> 6;
  int l   = tid & 63;
  int lo  = l & 31;        // point lane (B col / D col); weight row for A
  int hi  = l >> 5;        // k-half of the fragment
  int ch0 = hi * 8;
  int s   = blockIdx.x >> 2;
  int qg  = blockIdx.x & 3;

  // loop-invariant channel tables (8 channels per half-wave)
  float wox[8], woy[8], woz[8], wdd[8], wvv[8];
  *(float4*)&wox[0] = *(const float4*)&wpo[ch0];      *(float4*)&wox[4] = *(const float4*)&wpo[ch0+4];
  *(float4*)&woy[0] = *(const float4*)&wpo[16+ch0];   *(float4*)&woy[4] = *(const float4*)&wpo[16+ch0+4];
  *(float4*)&woz[0] = *(const float4*)&wpo[32+ch0];   *(float4*)&woz[4] = *(const float4*)&wpo[32+ch0+4];
  *(float4*)&wdd[0] = *(const float4*)&wpd[ch0];      *(float4*)&wdd[4] = *(const float4*)&wpd[ch0+4];
  *(float4*)&wvv[0] = *(const float4*)&wpv[ch0];      *(float4*)&wvv[4] = *(const float4*)&wpv[ch0+4];

  // A-fragments = W^T: A[m=lo][k=ch0+j] = W[ch0+j][lo]; zero rows m>=16.
  bf16x8 A1, A2, A3;
  #pragma unroll
  for (int j = 0; j < 8; ++j){ A1[j] = 0; A2[j] = 0; A3[j] = 0; }
  if (lo < 16){
    #pragma unroll
    for (int j = 0; j < 8; ++j){
      A1[j] = (short)f2b(w1[(ch0+j)*16 + lo]);
      A2[j] = (short)f2b(w2[(ch0+j)*16 + lo]);
      A3[j] = (short)f2b(w3[(ch0+j)*16 + lo]);
    }
  }
  f32x16 Z;
  #pragma unroll
  for (int i = 0; i < 16; ++i) Z[i] = 0.f;

  #pragma unroll 1
  for (int q4 = 0; q4 < 4; ++q4){
    int q  = qg*8 + w*4 + q4;
    int sq = s*Q_ + q;
    float qx = qrp[sq*3+0], qy = qrp[sq*3+1], qz = qrp[sq*3+2];
    int   qu = quid[sq];
    float rp[8];
    *(float4*)&rp[0] = *(const float4*)&rowproj[(size_t)sq*CP_ + ch0];
    *(float4*)&rp[4] = *(const float4*)&rowproj[(size_t)sq*CP_ + ch0 + 4];

    #pragma unroll 1
    for (int kb = 0; kb < 4; ++kb){
      int k  = kb*32 + lo;
      int sk = s*K_ + k;
      int j  = q2k[sk];
      float kx = qrp[j*3+0], ky = qrp[j*3+1], kz = qrp[j*3+2];
      int   ku = uid[j];
      float cp[8];
      *(float4*)&cp[0] = *(const float4*)&colproj[(size_t)j*CP_ + ch0];
      *(float4*)&cp[4] = *(const float4*)&colproj[(size_t)j*CP_ + ch0 + 4];

      float ox = qx - kx, oy = qy - ky, oz = qz - kz;
      float vf = (qu == ku) ? 1.f : 0.f;
      float invd = vf / (1.f + ox*ox + oy*oy + oz*oz);

      float p[8];
      #pragma unroll
      for (int jj = 0; jj < 8; ++jj)
        p[jj] = rp[jj] + cp[jj]
              + vf*(ox*wox[jj] + oy*woy[jj] + oz*woz[jj])
              + invd*wdd[jj] + vf*wvv[jj];

      // ---- L1: B = relu(p) (lane=point, k=ch0+j) ----
      bf16x8 bfr;
      #pragma unroll
      for (int jj = 0; jj < 8; ++jj) bfr[jj] = (short)f2b(fmaxf(p[jj], 0.f));
      f32x16 d = __builtin_amdgcn_mfma_f32_32x32x16_bf16(A1, bfr, Z, 0, 0, 0);

      // lane^32 exchange -> next B fragment (rows 0..15 of D)
      float t[8];
      #pragma unroll
      for (int r = 0; r < 8; ++r) t[r] = __shfl_xor(d[r], 32, 64);
      #pragma unroll
      for (int jj = 0; jj < 4; ++jj){
        float v0 = hi ? t[jj+4] : d[jj];
        float v1 = hi ? d[jj+4] : t[jj];
        bfr[jj]   = (short)f2b(fmaxf(v0, 0.f));
        bfr[jj+4] = (short)f2b(fmaxf(v1, 0.f));
      }
      // ---- L2 ----
      d = __builtin_amdgcn_mfma_f32_32x32x16_bf16(A2, bfr, Z, 0, 0, 0);
      #pragma unroll
      for (int r = 0; r < 8; ++r) t[r] = __shfl_xor(d[r], 32, 64);
      #pragma unroll
      for (int jj = 0; jj < 4; ++jj){
        float v0 = hi ? t[jj+4] : d[jj];
        float v1 = hi ? d[jj+4] : t[jj];
        bfr[jj]   = (short)f2b(fmaxf(v0, 0.f));
        bfr[jj+4] = (short)f2b(fmaxf(v1, 0.f));
      }
      // ---- L3 ----
      d = __builtin_amdgcn_mfma_f32_32x32x16_bf16(A3, bfr, Z, 0, 0, 0);
      #pragma unroll
      for (int r = 0; r < 8; ++r) t[r] = __shfl_xor(d[r], 32, 64);
      float pout[8];
      #pragma unroll
      for (int jj = 0; jj < 4; ++jj){
        pout[jj]   = p[jj]   + (hi ? t[jj+4] : d[jj]);
        pout[jj+4] = p[jj+4] + (hi ? d[jj+4] : t[jj]);
      }

      // store out_pair (residual + MLP), 32B per lane
      size_t ob = ((size_t)sq*K_ + k)*CP_ + ch0;
      *(float4*)&out_pair[ob]     = make_float4(pout[0], pout[1], pout[2], pout[3]);
      *(float4*)&out_pair[ob + 4] = make_float4(pout[4], pout[5], pout[6], pout[7]);

      // bias: b[h] = sum_c pout[c]*wb[c][h]; combine channel halves via shfl
      float b0 = 0.f, b1 = 0.f, b2 = 0.f, b3 = 0.f;
      #pragma unroll
      for (int jj = 0; jj < 8; ++jj){
        float4 wv4 = *(const float4*)&wb[(ch0+jj)*4];
        float pj = pout[jj];
        b0 += pj*wv4.x; b1 += pj*wv4.y; b2 += pj*wv4.z; b3 += pj*wv4.w;
      }
      b0 += __shfl_xor(b0, 32, 64);
      b1 += __shfl_xor(b1, 32, 64);
      b2 += __shfl_xor(b2, 32, 64);
      b3 += __shfl_xor(b3, 32, 64);
      if (hi == 0){
        size_t bb = (((size_t)s*H_ + 0)*Q_ + q)*K_ + k;
        bias_ws[bb]             = f2b(b0);
        bias_ws[bb + Q_*K_]     = f2b(b1);
        bias_ws[bb + 2*Q_*K_]   = f2b(b2);
        bias_ws[bb + 3*Q_*K_]   = f2b(b3);
      }
    }
  }
}

// ---- N6: attention. One 128-thread block per (s,h). K/V staged in LDS (pitch 36). ----
__global__ __launch_bounds__(128) void n_attn(
    const float* __restrict__ Qp, const float* __restrict__ Kp, const float* __restrict__ Vp,
    const float* __restrict__ qmask, const u16* __restrict__ bias_ws, const int* __restrict__ q2k,
    float* __restrict__ O)
{
  __shared__ float Ks[128*36];
  __shared__ float Vs[128*36];
  __shared__ float msk[128];
  __shared__ float redm[64];
  __shared__ float reds[64];
  __shared__ float Osm[32*33];

  int b = blockIdx.x;
  int s = b >> 2, h = b & 3;
  int sq0 = s * Q_;
  int base = s * K_;
  int t = threadIdx.x;

  {
    int e = t & 7, rr = t >> 3;
    #pragma unroll
    for (int it = 0; it < 8; ++it){
      int row = it*16 + rr;
      int j = q2k[base + row];
      const float4* ksrc = (const float4*)&Kp[(size_t)j*CA_ + h*DH_];
      const float4* vsrc = (const float4*)&Vp[(size_t)j*CA_ + h*DH_];
      *(float4*)&Ks[row*36 + e*4] = ksrc[e];
      *(float4*)&Vs[row*36 + e*4] = vsrc[e];
    }
    int j0 = q2k[base + t];
    msk[t] = qmask[j0];
  }

  int q  = t & 31;
  int kr = t >> 5;
  float qreg[32];
  {
    const float4* qsrc = (const float4*)&Qp[(size_t)(sq0+q)*CA_ + h*DH_];
    #pragma unroll
    for (int d4 = 0; d4 < 8; ++d4){
      float4 v = qsrc[d4];
      qreg[d4*4+0] = v.x; qreg[d4*4+1] = v.y; qreg[d4*4+2] = v.z; qreg[d4*4+3] = v.w;
    }
  }

  u32 bw[16];
  {
    const uint4* bsrc = (const uint4*)&bias_ws[(((size_t)s*H_ + h)*Q_ + q)*K_ + kr*32];
    uint4 B;
    B = bsrc[0]; bw[0]=B.x;  bw[1]=B.y;  bw[2]=B.z;  bw[3]=B.w;
    B = bsrc[1]; bw[4]=B.x;  bw[5]=B.y;  bw[6]=B.z;  bw[7]=B.w;
    B = bsrc[2]; bw[8]=B.x;  bw[9]=B.y;  bw[10]=B.z; bw[11]=B.w;
    B = bsrc[3]; bw[12]=B.x; bw[13]=B.y; bw[14]=B.z; bw[15]=B.w;
  }
  __syncthreads();

  float p[32];
  #pragma unroll
  for (int kk = 0; kk < 32; ++kk){
    int k = kr*32 + kk;
    const float* kbase = &Ks[k*36];
    float acc = 0.f;
    #pragma unroll
    for (int d4 = 0; d4 < 8; ++d4){
      float4 kv = *(const float4*)(kbase + d4*4);
      acc += qreg[d4*4+0]*kv.x + qreg[d4*4+1]*kv.y + qreg[d4*4+2]*kv.z + qreg[d4*4+3]*kv.w;
    }
    float bz = b2f((u16)((bw[kk>>1] >> ((kk&1)*16)) & 0xffffu));
    p[kk] = (msk[k] > 0.f) ? (acc + bz) : -1e9f;
  }

  float m = p[0];
  #pragma unroll
  for (int kk = 1; kk < 32; ++kk) m = fmaxf(m, p[kk]);
  m = fmaxf(m, __shfl_xor(m, 32, 64));
  int wv = t >> 6;
  if ((t & 63) < 32) redm[wv*32 + q] = m;
  __syncthreads();
  float M = fmaxf(redm[q], redm[32 + q]);

  float sm = 0.f;
  #pragma unroll
  for (int kk = 0; kk < 32; ++kk){ p[kk] = __expf(p[kk] - M); sm += p[kk]; }
  sm += __shfl_xor(sm, 32, 64);
  if ((t & 63) < 32) reds[wv*32 + q] = sm;
  __syncthreads();
  float inv = 1.f / (reds[q] + reds[32 + q]);

  float acc[32];
  #pragma unroll
  for (int d = 0; d < 32; ++d) acc[d] = 0.f;
  #pragma unroll
  for (int kk = 0; kk < 32; ++kk){
    float w = p[kk];
    const float* vbase = &Vs[(kr*32 + kk)*36];
    #pragma unroll
    for (int d4 = 0; d4 < 8; ++d4){
      float4 vv = *(const float4*)(vbase + d4*4);
      acc[d4*4+0] += w*vv.x; acc[d4*4+1] += w*vv.y; acc[d4*4+2] += w*vv.z; acc[d4*4+3] += w*vv.w;
    }
  }
  #pragma unroll
  for (int d = 0; d < 32; ++d) acc[d] += __shfl_xor(acc[d], 32, 64);
  if (t < 32){
    #pragma unroll
    for (int d = 0; d < 32; ++d) Osm[q*33 + d] = acc[d];
  }
  __syncthreads();
  if (t >= 64 && t < 96){
    #pragma unroll
    for (int d = 0; d < 32; ++d) Osm[q*33 + d] = (Osm[q*33 + d] + acc[d]) * inv;
  }
  __syncthreads();

  #pragma unroll
  for (int it = 0; it < 2; ++it){
    int idx = it*128 + t;
    int qq = idx >> 3, e = idx & 7;
    float4 v = make_float4(Osm[qq*33 + e*4 + 0], Osm[qq*33 + e*4 + 1],
                           Osm[qq*33 + e*4 + 2], Osm[qq*33 + e*4 + 3]);
    *(float4*)&O[(size_t)(sq0+qq)*CA_ + h*DH_ + e*4] = v;
  }
}

// ---- N7: queries_act = (qsc + O @ wo) * qmask -> out_skip only ----
__global__ __launch_bounds__(128) void n_qact(
    const float* __restrict__ qsc, const float* __restrict__ O, const float* __restrict__ qmask,
    const float* __restrict__ wo, float* __restrict__ out_skip)
{
  int c = threadIdx.x;
  size_t r0 = (size_t)blockIdx.x * 16;
  float acc[16];
  #pragma unroll
  for (int r = 0; r < 16; ++r) acc[r] = 0.f;
  #pragma unroll 4
  for (int i = 0; i < CA_; ++i){
    float w = wo[i*CA_+c];
    #pragma unroll
    for (int r = 0; r < 16; ++r) acc[r] += O[(r0+r)*CA_+i] * w;
  }
  #pragma unroll
  for (int r = 0; r < 16; ++r){
    float v = (qsc[(r0+r)*CA_+c] + acc[r]) * qmask[r0+r];
    out_skip[(r0+r)*CA_+c] = v;
  }
}

// ---- N8: proj + gather + masked mean (reads out_skip) ----
__global__ __launch_bounds__(384) void n_tok(
    const float* __restrict__ qact, const int* __restrict__ q2t, const float* __restrict__ amask,
    const float* __restrict__ wp, float* __restrict__ out_tok)
{
  int t = blockIdx.x, ct = threadIdx.x;
  int jd[D_];
  float mk[D_];
  #pragma unroll
  for (int d = 0; d < D_; ++d){
    jd[d] = q2t[t*D_ + d];
    mk[d] = amask[t*D_ + d];
  }
  float acc[D_];
  #pragma unroll
  for (int d = 0; d < D_; ++d) acc[d] = 0.f;
  #pragma unroll 4
  for (int i = 0; i < CA_; ++i){
    float w = wp[i*CT_ + ct];
    #pragma unroll
    for (int d = 0; d < D_; ++d) acc[d] += qact[(size_t)jd[d]*CA_ + i] * w;
  }
  float num = 0.f, den = 1e-10f;
  #pragma unroll
  for (int d = 0; d < D_; ++d){
    num += mk[d] * fmaxf(acc[d], 0.f);
    den += mk[d];
  }
  out_tok[(size_t)t*CT_ + ct] = num/den;
}

extern "C" void kernel_launch(void* const* d_in, const int* in_sizes, int n_in,
                              void* d_out, int out_size, void* d_ws, size_t ws_size,
                              hipStream_t stream) {
  (void)in_sizes; (void)n_in; (void)out_size; (void)ws_size;
  const float* ref_positions = (const float*)d_in[0];
  const float* ref_mask      = (const float*)d_in[1];
  const float* ref_charge    = (const float*)d_in[2];
  const float* atom_mask     = (const float*)d_in[3];
  const int*   ref_element   = (const int*)d_in[4];
  const int*   ref_chars     = (const int*)d_in[5];
  const int*   ref_uid       = (const int*)d_in[6];
  const int*   t2q           = (const int*)d_in[7];
  const int*   q2k           = (const int*)d_in[8];
  const int*   q2t           = (const int*)d_in[9];
  const float* w_ref_pos     = (const float*)d_in[10];
  const float* w_ref_mask    = (const float*)d_in[11];
  const float* w_ref_element = (const float*)d_in[12];
  const float* w_ref_charge  = (const float*)d_in[13];
  const float* w_ref_name    = (const float*)d_in[14];
  const float* w_s2p_row1    = (const float*)d_in[15];
  const float* w_s2p_col1    = (const float*)d_in[16];
  const float* w_pair_off1   = (const float*)d_in[17];
  const float* w_pair_dist1  = (const float*)d_in[18];
  const float* w_pair_valid  = (const float*)d_in[19];
  const float* w_mlp1        = (const float*)d_in[20];
  const float* w_mlp2        = (const float*)d_in[21];
  const float* w_mlp3        = (const float*)d_in[22];
  const float* wq            = (const float*)d_in[23];
  const float* wk            = (const float*)d_in[24];
  const float* wv            = (const float*)d_in[25];
  const float* wb            = (const float*)d_in[26];
  const float* wo            = (const float*)d_in[27];
  const float* w_proj        = (const float*)d_in[28];

  char* ws = (char*)d_ws;
  float* qrp     = (float*)(ws + 9732096);
  int*   quid    = (int*)  (ws + 9953280);
  float* rowproj = (float*)(ws + 11206656);
  float* colproj = (float*)(ws + 12386304);
  float* Qp      = (float*)(ws + 13565952);
  float* Kp      = (float*)(ws + 23003136);
  float* Vp      = (float*)(ws + 32440320);
  float* O       = (float*)(ws + 41877504);
  u16*   biasws  = (u16*)  (ws + 60751872);

  float* out = (float*)d_out;
  float* out_tok   = out + 0;
  float* out_skip  = out + 294912;
  float* out_qmask = out + 2654208;
  float* out_qsc   = out + 2672640;
  float* out_kmask = out + 5031936;
  float* out_ksc   = out + 5105664;
  float* out_pair  = out + 14542848;

  hipLaunchKernelGGL(n_qsc, dim3(SQ_/8), dim3(128), 0, stream,
      ref_positions, ref_mask, ref_charge, atom_mask, ref_element, ref_chars, ref_uid, t2q,
      w_ref_pos, w_ref_mask, w_ref_element, w_ref_charge, w_ref_name,
      qrp, quid, out_qsc, out_qmask);
  hipLaunchKernelGGL(n_keys, dim3(SK_/16), dim3(128), 0, stream,
      out_qsc, out_qmask, q2k, out_ksc, out_kmask);
  hipLaunchKernelGGL(n_qkv, dim3(SQ_/16), dim3(128), 0, stream,
      out_qsc, wq, wk, wv, Qp, Kp, Vp);
  hipLaunchKernelGGL(n_proj16b, dim3(SQ_/4), dim3(128), 0, stream,
      out_qsc, w_s2p_row1, w_s2p_col1, rowproj, colproj);
  hipLaunchKernelGGL(n_pair, dim3(S_*4), dim3(128), 0, stream,
      q2k, rowproj, colproj, qrp, quid, ref_uid,
      w_mlp1, w_mlp2, w_mlp3, w_pair_off1, w_pair_dist1, w_pair_valid, wb,
      out_pair, biasws);
  hipLaunchKernelGGL(n_attn, dim3(S_*H_), dim3(128), 0, stream,
      Qp, Kp, Vp, out_qmask, biasws, q2k, O);
  hipLaunchKernelGGL(n_qact, dim3(SQ_/16), dim3(128), 0, stream,
      out_qsc, O, out_qmask, wo, out_skip);
  hipLaunchKernelGGL(n_tok, dim3(T_), dim3(384), 0, stream,
      out_skip, q2t, atom_mask, w_proj, out_tok);
}

// Round 11
// 515.305 us; speedup vs baseline: 1.2278x; 1.0340x over previous
//
#include <hip/hip_runtime.h>

typedef unsigned short u16;
typedef unsigned int u32;
typedef short bf16x8 __attribute__((ext_vector_type(8)));
typedef float f32x16 __attribute__((ext_vector_type(16)));

#define T_ 768
#define D_ 24
#define S_ 576
#define Q_ 32
#define K_ 128
#define CA_ 128
#define CP_ 16
#define CT_ 384
#define H_ 4
#define DH_ 32
#define SQ_ (S_*Q_)
#define SK_ (S_*K_)

__device__ __forceinline__ float b2f(u16 u){ return __uint_as_float(((u32)u)<<16); }
__device__ __forceinline__ u16 f2b(float f){ u32 x=__float_as_uint(f); return (u16)((x + 0x7fffu + ((x>>16)&1u))>>16); }

// Compiler-order fence for intra-wave LDS exchange (no runtime cost).
__device__ __forceinline__ void wave_fence(){
  __builtin_amdgcn_sched_barrier(0);
  __builtin_amdgcn_wave_barrier();
  __builtin_amdgcn_sched_barrier(0);
}

// ---- N1: per-atom conditioning gathered to query slots (8 slots/block) ----
__global__ __launch_bounds__(128) void n_qsc(
    const float* __restrict__ pos, const float* __restrict__ rmask, const float* __restrict__ charge,
    const float* __restrict__ amask, const int* __restrict__ elem, const int* __restrict__ chars,
    const int* __restrict__ uid, const int* __restrict__ t2q,
    const float* __restrict__ w_pos, const float* __restrict__ w_mask, const float* __restrict__ w_elem,
    const float* __restrict__ w_chg, const float* __restrict__ w_name,
    float* __restrict__ qrp, int* __restrict__ quid,
    float* __restrict__ out_qsc, float* __restrict__ out_qmask)
{
  int ch = threadIdx.x;
  #pragma unroll 1
  for (int sl = 0; sl < 8; ++sl){
    int slot = blockIdx.x*8 + sl;
    int a = t2q[slot];
    float p0 = pos[a*3+0], p1 = pos[a*3+1], p2 = pos[a*3+2];
    float m  = rmask[a];
    float cg = asinhf(charge[a]);
    int e  = elem[a];
    int c0 = chars[a*4+0], c1 = chars[a*4+1], c2 = chars[a*4+2], c3 = chars[a*4+3];
    float v = p0*w_pos[0*CA_+ch] + p1*w_pos[1*CA_+ch] + p2*w_pos[2*CA_+ch];
    v += m * w_mask[ch];
    v += w_elem[e*CA_+ch];
    v += cg * w_chg[ch];
    v += w_name[(0*64+c0)*CA_+ch] + w_name[(1*64+c1)*CA_+ch]
       + w_name[(2*64+c2)*CA_+ch] + w_name[(3*64+c3)*CA_+ch];
    v *= m;
    out_qsc[(size_t)slot*CA_+ch] = v;
    if (ch < 3) qrp[slot*3+ch] = pos[a*3+ch];
    if (ch == 0){
      out_qmask[slot] = amask[a];
      quid[slot] = uid[a];
    }
  }
}

// ---- N2: key-space gathers (pure copy). 16 rows/block ----
__global__ __launch_bounds__(128) void n_keys(
    const float* __restrict__ qsc, const float* __restrict__ qmask, const int* __restrict__ q2k,
    float* __restrict__ out_ksc, float* __restrict__ out_kmask)
{
  int e = threadIdx.x & 31;
  int rr = threadIdx.x >> 5;
  #pragma unroll
  for (int it = 0; it < 4; ++it){
    int sk = blockIdx.x*16 + it*4 + rr;
    int j = q2k[sk];
    *(float4*)&out_ksc[(size_t)sk*CA_ + e*4] = *(const float4*)&qsc[(size_t)j*CA_ + e*4];
    if (e == 0) out_kmask[sk] = qmask[j];
  }
}

// ---- N3: fused QKV projection ----
__global__ __launch_bounds__(128) void n_qkv(
    const float* __restrict__ X, const float* __restrict__ wq, const float* __restrict__ wk,
    const float* __restrict__ wv, float* __restrict__ Qp, float* __restrict__ Kp, float* __restrict__ Vp)
{
  int c = threadIdx.x;
  size_t r0 = (size_t)blockIdx.x * 16;
  float aq[16], ak[16], av[16];
  #pragma unroll
  for (int r = 0; r < 16; ++r){ aq[r] = 0.f; ak[r] = 0.f; av[r] = 0.f; }
  #pragma unroll 4
  for (int i = 0; i < CA_; ++i){
    float q = wq[i*CA_+c];
    float k = wk[i*CA_+c];
    float v = wv[i*CA_+c];
    #pragma unroll
    for (int r = 0; r < 16; ++r){
      float x = X[(r0+r)*CA_ + i];
      aq[r] += x * q;
      ak[r] += x * k;
      av[r] += x * v;
    }
  }
  #pragma unroll
  for (int r = 0; r < 16; ++r){
    Qp[(r0+r)*CA_+c] = aq[r] * 0.17677669529663687f;
    Kp[(r0+r)*CA_+c] = ak[r];
    Vp[(r0+r)*CA_+c] = av[r];
  }
}

// ---- N4: fused row+col 128->16 relu-linear ----
__global__ __launch_bounds__(128) void n_proj16b(
    const float* __restrict__ X, const float* __restrict__ Wr, const float* __restrict__ Wc,
    float* __restrict__ Yr, float* __restrict__ Yc)
{
  int row = blockIdx.x*4 + (threadIdx.x >> 5);
  int c = threadIdx.x & 31;
  const float* W = (c < 16) ? Wr : Wc;
  float* Y = (c < 16) ? Yr : Yc;
  int cc = c & 15;
  float acc = 0.f;
  for (int i = 0; i < CA_; ++i)
    acc += fmaxf(X[(size_t)row*CA_+i], 0.f) * W[i*CP_+cc];
  Y[(size_t)row*CP_+cc] = acc;
}

// ---- N5: pair conditioning + MLP via bf16 MFMA (r9-verified) ----
__global__ __launch_bounds__(128) void n_pair(
    const int* __restrict__ q2k, const float* __restrict__ rowproj, const float* __restrict__ colproj,
    const float* __restrict__ qrp, const int* __restrict__ quid, const int* __restrict__ uid,
    const float* __restrict__ w1, const float* __restrict__ w2, const float* __restrict__ w3,
    const float* __restrict__ wpo, const float* __restrict__ wpd, const float* __restrict__ wpv,
    const float* __restrict__ wb,
    float* __restrict__ out_pair, u16* __restrict__ bias_ws)
{
  int tid = threadIdx.x;
  int w   = tid >> 6;
  int l   = tid & 63;
  int lo  = l & 31;
  int hi  = l >> 5;
  int ch0 = hi * 8;
  int s   = blockIdx.x >> 2;
  int qg  = blockIdx.x & 3;

  float wox[8], woy[8], woz[8], wdd[8], wvv[8];
  *(float4*)&wox[0] = *(const float4*)&wpo[ch0];      *(float4*)&wox[4] = *(const float4*)&wpo[ch0+4];
  *(float4*)&woy[0] = *(const float4*)&wpo[16+ch0];   *(float4*)&woy[4] = *(const float4*)&wpo[16+ch0+4];
  *(float4*)&woz[0] = *(const float4*)&wpo[32+ch0];   *(float4*)&woz[4] = *(const float4*)&wpo[32+ch0+4];
  *(float4*)&wdd[0] = *(const float4*)&wpd[ch0];      *(float4*)&wdd[4] = *(const float4*)&wpd[ch0+4];
  *(float4*)&wvv[0] = *(const float4*)&wpv[ch0];      *(float4*)&wvv[4] = *(const float4*)&wpv[ch0+4];

  bf16x8 A1, A2, A3;
  #pragma unroll
  for (int j = 0; j < 8; ++j){ A1[j] = 0; A2[j] = 0; A3[j] = 0; }
  if (lo < 16){
    #pragma unroll
    for (int j = 0; j < 8; ++j){
      A1[j] = (short)f2b(w1[(ch0+j)*16 + lo]);
      A2[j] = (short)f2b(w2[(ch0+j)*16 + lo]);
      A3[j] = (short)f2b(w3[(ch0+j)*16 + lo]);
    }
  }
  f32x16 Z;
  #pragma unroll
  for (int i = 0; i < 16; ++i) Z[i] = 0.f;

  #pragma unroll 1
  for (int q4 = 0; q4 < 4; ++q4){
    int q  = qg*8 + w*4 + q4;
    int sq = s*Q_ + q;
    float qx = qrp[sq*3+0], qy = qrp[sq*3+1], qz = qrp[sq*3+2];
    int   qu = quid[sq];
    float rp[8];
    *(float4*)&rp[0] = *(const float4*)&rowproj[(size_t)sq*CP_ + ch0];
    *(float4*)&rp[4] = *(const float4*)&rowproj[(size_t)sq*CP_ + ch0 + 4];

    #pragma unroll 1
    for (int kb = 0; kb < 4; ++kb){
      int k  = kb*32 + lo;
      int sk = s*K_ + k;
      int j  = q2k[sk];
      float kx = qrp[j*3+0], ky = qrp[j*3+1], kz = qrp[j*3+2];
      int   ku = uid[j];
      float cp[8];
      *(float4*)&cp[0] = *(const float4*)&colproj[(size_t)j*CP_ + ch0];
      *(float4*)&cp[4] = *(const float4*)&colproj[(size_t)j*CP_ + ch0 + 4];

      float ox = qx - kx, oy = qy - ky, oz = qz - kz;
      float vf = (qu == ku) ? 1.f : 0.f;
      float invd = vf / (1.f + ox*ox + oy*oy + oz*oz);

      float p[8];
      #pragma unroll
      for (int jj = 0; jj < 8; ++jj)
        p[jj] = rp[jj] + cp[jj]
              + vf*(ox*wox[jj] + oy*woy[jj] + oz*woz[jj])
              + invd*wdd[jj] + vf*wvv[jj];

      bf16x8 bfr;
      #pragma unroll
      for (int jj = 0; jj < 8; ++jj) bfr[jj] = (short)f2b(fmaxf(p[jj], 0.f));
      f32x16 d = __builtin_amdgcn_mfma_f32_32x32x16_bf16(A1, bfr, Z, 0, 0, 0);

      float t[8];
      #pragma unroll
      for (int r = 0; r < 8; ++r) t[r] = __shfl_xor(d[r], 32, 64);
      #pragma unroll
      for (int jj = 0; jj < 4; ++jj){
        float v0 = hi ? t[jj+4] : d[jj];
        float v1 = hi ? d[jj+4] : t[jj];
        bfr[jj]   = (short)f2b(fmaxf(v0, 0.f));
        bfr[jj+4] = (short)f2b(fmaxf(v1, 0.f));
      }
      d = __builtin_amdgcn_mfma_f32_32x32x16_bf16(A2, bfr, Z, 0, 0, 0);
      #pragma unroll
      for (int r = 0; r < 8; ++r) t[r] = __shfl_xor(d[r], 32, 64);
      #pragma unroll
      for (int jj = 0; jj < 4; ++jj){
        float v0 = hi ? t[jj+4] : d[jj];
        float v1 = hi ? d[jj+4] : t[jj];
        bfr[jj]   = (short)f2b(fmaxf(v0, 0.f));
        bfr[jj+4] = (short)f2b(fmaxf(v1, 0.f));
      }
      d = __builtin_amdgcn_mfma_f32_32x32x16_bf16(A3, bfr, Z, 0, 0, 0);
      #pragma unroll
      for (int r = 0; r < 8; ++r) t[r] = __shfl_xor(d[r], 32, 64);
      float pout[8];
      #pragma unroll
      for (int jj = 0; jj < 4; ++jj){
        pout[jj]   = p[jj]   + (hi ? t[jj+4] : d[jj]);
        pout[jj+4] = p[jj+4] + (hi ? d[jj+4] : t[jj]);
      }

      size_t ob = ((size_t)sq*K_ + k)*CP_ + ch0;
      *(float4*)&out_pair[ob]     = make_float4(pout[0], pout[1], pout[2], pout[3]);
      *(float4*)&out_pair[ob + 4] = make_float4(pout[4], pout[5], pout[6], pout[7]);

      float b0 = 0.f, b1 = 0.f, b2 = 0.f, b3 = 0.f;
      #pragma unroll
      for (int jj = 0; jj < 8; ++jj){
        float4 wv4 = *(const float4*)&wb[(ch0+jj)*4];
        float pj = pout[jj];
        b0 += pj*wv4.x; b1 += pj*wv4.y; b2 += pj*wv4.z; b3 += pj*wv4.w;
      }
      b0 += __shfl_xor(b0, 32, 64);
      b1 += __shfl_xor(b1, 32, 64);
      b2 += __shfl_xor(b2, 32, 64);
      b3 += __shfl_xor(b3, 32, 64);
      if (hi == 0){
        size_t bb = (((size_t)s*H_ + 0)*Q_ + q)*K_ + k;
        bias_ws[bb]             = f2b(b0);
        bias_ws[bb + Q_*K_]     = f2b(b1);
        bias_ws[bb + 2*Q_*K_]   = f2b(b2);
        bias_ws[bb + 3*Q_*K_]   = f2b(b3);
      }
    }
  }
}

// ---- N6: attention via bf16 MFMA. One 64-thread wave per (s,h).
//      QK^T swapped (A=K-tile, B=Q) -> D lane = q: softmax is per-lane over 64 regs
//      + one shfl_xor(32). PV: A=V (rows=d), B=P via the r9-verified half-exchange.
//      O transposed through a 32x33 LDS tile (aliased over the bias buffer). ----
__global__ __launch_bounds__(64) void n_attn(
    const float* __restrict__ Qp, const float* __restrict__ Kp, const float* __restrict__ Vp,
    const float* __restrict__ kmask, const u16* __restrict__ bias_ws, const int* __restrict__ q2k,
    float* __restrict__ O)
{
  __shared__ float Ls[32*129];   // bias f32 tile; later aliased as 32x33 O-transpose
  __shared__ float msk[K_];
  int t  = threadIdx.x;
  int lo = t & 31, hi = t >> 5;
  int b = blockIdx.x;
  int s = b >> 2, h = b & 3;
  int sq0 = s*Q_, base = s*K_;

  // masks (coalesced, contiguous)
  msk[t]      = kmask[base + t];
  msk[64 + t] = kmask[base + 64 + t];

  // bias tile -> f32 LDS, pitch 129 (conflict-free reads: bank = lo + k mod 32)
  {
    const uint2* bsrc = (const uint2*)&bias_ws[(size_t)(s*H_ + h)*Q_*K_];
    #pragma unroll
    for (int i = 0; i < 16; ++i){
      int idx = i*64 + t;
      int q = idx >> 5, e = (idx & 31)*4;
      uint2 v = bsrc[idx];
      float* dst = &Ls[q*129 + e];
      dst[0] = b2f((u16)(v.x & 0xffffu));
      dst[1] = b2f((u16)(v.x >> 16));
      dst[2] = b2f((u16)(v.y & 0xffffu));
      dst[3] = b2f((u16)(v.y >> 16));
    }
  }

  // Q B-operand frags (lane = col = q = lo); d-chunks [0,16) and [16,32)
  bf16x8 Bq1, Bq2;
  {
    const float* qrow = &Qp[(size_t)(sq0+lo)*CA_ + h*DH_];
    float4 x0 = *(const float4*)&qrow[hi*8];
    float4 x1 = *(const float4*)&qrow[hi*8+4];
    float4 x2 = *(const float4*)&qrow[16+hi*8];
    float4 x3 = *(const float4*)&qrow[16+hi*8+4];
    Bq1[0]=(short)f2b(x0.x); Bq1[1]=(short)f2b(x0.y); Bq1[2]=(short)f2b(x0.z); Bq1[3]=(short)f2b(x0.w);
    Bq1[4]=(short)f2b(x1.x); Bq1[5]=(short)f2b(x1.y); Bq1[6]=(short)f2b(x1.z); Bq1[7]=(short)f2b(x1.w);
    Bq2[0]=(short)f2b(x2.x); Bq2[1]=(short)f2b(x2.y); Bq2[2]=(short)f2b(x2.z); Bq2[3]=(short)f2b(x2.w);
    Bq2[4]=(short)f2b(x3.x); Bq2[5]=(short)f2b(x3.y); Bq2[6]=(short)f2b(x3.z); Bq2[7]=(short)f2b(x3.w);
  }

  f32x16 Z;
  #pragma unroll
  for (int i = 0; i < 16; ++i) Z[i] = 0.f;

  // QK^T: 4 k-tiles x 2 accumulating MFMAs (A = K-tile, rows = k_local)
  f32x16 Sar[4];
  #pragma unroll
  for (int n = 0; n < 4; ++n){
    int jkn = q2k[base + 32*n + lo];
    const float* krow = &Kp[(size_t)jkn*CA_ + h*DH_];
    float4 x0 = *(const float4*)&krow[hi*8];
    float4 x1 = *(const float4*)&krow[hi*8+4];
    float4 x2 = *(const float4*)&krow[16+hi*8];
    float4 x3 = *(const float4*)&krow[16+hi*8+4];
    bf16x8 Ak1, Ak2;
    Ak1[0]=(short)f2b(x0.x); Ak1[1]=(short)f2b(x0.y); Ak1[2]=(short)f2b(x0.z); Ak1[3]=(short)f2b(x0.w);
    Ak1[4]=(short)f2b(x1.x); Ak1[5]=(short)f2b(x1.y); Ak1[6]=(short)f2b(x1.z); Ak1[7]=(short)f2b(x1.w);
    Ak2[0]=(short)f2b(x2.x); Ak2[1]=(short)f2b(x2.y); Ak2[2]=(short)f2b(x2.z); Ak2[3]=(short)f2b(x2.w);
    Ak2[4]=(short)f2b(x3.x); Ak2[5]=(short)f2b(x3.y); Ak2[6]=(short)f2b(x3.z); Ak2[7]=(short)f2b(x3.w);
    f32x16 d = __builtin_amdgcn_mfma_f32_32x32x16_bf16(Ak1, Bq1, Z, 0, 0, 0);
    Sar[n]   = __builtin_amdgcn_mfma_f32_32x32x16_bf16(Ak2, Bq2, d, 0, 0, 0);
  }

  wave_fence();   // LDS staging visible before reads (intra-wave)

  // logits + per-lane softmax (lane = q = lo; reg (n,r) -> k = 32n + (r&3)+8(r>>2)+4hi)
  float e_[4][16];
  float mx = -1e30f;
  #pragma unroll
  for (int n = 0; n < 4; ++n){
    #pragma unroll
    for (int r = 0; r < 16; ++r){
      int k = 32*n + (r&3) + 8*(r>>2) + 4*hi;
      float lg = (msk[k] > 0.f) ? (Sar[n][r] + Ls[lo*129 + k]) : -1e9f;
      e_[n][r] = lg;
      mx = fmaxf(mx, lg);
    }
  }
  mx = fmaxf(mx, __shfl_xor(mx, 32, 64));
  float sm = 0.f;
  #pragma unroll
  for (int n = 0; n < 4; ++n){
    #pragma unroll
    for (int r = 0; r < 16; ++r){
      float ee = __expf(e_[n][r] - mx);
      e_[n][r] = ee;
      sm += ee;
    }
  }
  sm += __shfl_xor(sm, 32, 64);
  float inv = 1.f / sm;

  // PV: 8 accumulating MFMAs. A = V (rows = d), B = P (cols = q) via half-exchange.
  f32x16 Dpv = Z;
  #pragma unroll
  for (int mt = 0; mt < 8; ++mt){
    bf16x8 Av;
    #pragma unroll
    for (int j = 0; j < 8; ++j){
      int kk = 16*mt + hi*8 + j;
      int jv = q2k[base + kk];            // uniform within half -> broadcast
      Av[j] = (short)f2b(Vp[(size_t)jv*CA_ + h*DH_ + lo]);
    }
    bf16x8 Bp;
    int n  = mt >> 1;
    int m1 = mt & 1;
    #pragma unroll
    for (int j = 0; j < 4; ++j){
      int r0 = j + 8*m1;
      int r1 = r0 + 4;
      float o0 = e_[n][r0];
      float o1 = e_[n][r1];
      float x0 = __shfl_xor(o0, 32, 64);
      float x1 = __shfl_xor(o1, 32, 64);
      Bp[j]   = (short)f2b(hi ? x1 : o0);   // slot j   (owner half 0 pattern)
      Bp[j+4] = (short)f2b(hi ? o1 : x0);   // slot j+4 (owner half 1 pattern)
    }
    Dpv = __builtin_amdgcn_mfma_f32_32x32x16_bf16(Av, Bp, Dpv, 0, 0, 0);
  }

  // O transpose via LDS alias (lane=q holds d-rows (r&3)+8(r>>2)+4hi) -> coalesced stores
  wave_fence();   // all Ls bias reads done before overwrite
  #pragma unroll
  for (int b2 = 0; b2 < 4; ++b2){
    *(float4*)&Ls[lo*33 + 8*b2 + 4*hi] =
      make_float4(Dpv[4*b2+0]*inv, Dpv[4*b2+1]*inv, Dpv[4*b2+2]*inv, Dpv[4*b2+3]*inv);
  }
  wave_fence();
  #pragma unroll
  for (int it = 0; it < 4; ++it){
    int fid = it*64 + t;
    int qq = fid >> 3, e4 = fid & 7;
    float4 v = make_float4(Ls[qq*33 + e4*4 + 0], Ls[qq*33 + e4*4 + 1],
                           Ls[qq*33 + e4*4 + 2], Ls[qq*33 + e4*4 + 3]);
    *(float4*)&O[(size_t)(sq0+qq)*CA_ + h*DH_ + e4*4] = v;
  }
}

// ---- N7: queries_act = (qsc + O @ wo) * qmask -> out_skip only ----
__global__ __launch_bounds__(128) void n_qact(
    const float* __restrict__ qsc, const float* __restrict__ O, const float* __restrict__ qmask,
    const float* __restrict__ wo, float* __restrict__ out_skip)
{
  int c = threadIdx.x;
  size_t r0 = (size_t)blockIdx.x * 16;
  float acc[16];
  #pragma unroll
  for (int r = 0; r < 16; ++r) acc[r] = 0.f;
  #pragma unroll 4
  for (int i = 0; i < CA_; ++i){
    float w = wo[i*CA_+c];
    #pragma unroll
    for (int r = 0; r < 16; ++r) acc[r] += O[(r0+r)*CA_+i] * w;
  }
  #pragma unroll
  for (int r = 0; r < 16; ++r){
    float v = (qsc[(r0+r)*CA_+c] + acc[r]) * qmask[r0+r];
    out_skip[(r0+r)*CA_+c] = v;
  }
}

// ---- N8: proj + gather + masked mean ----
__global__ __launch_bounds__(384) void n_tok(
    const float* __restrict__ qact, const int* __restrict__ q2t, const float* __restrict__ amask,
    const float* __restrict__ wp, float* __restrict__ out_tok)
{
  int t = blockIdx.x, ct = threadIdx.x;
  int jd[D_];
  float mk[D_];
  #pragma unroll
  for (int d = 0; d < D_; ++d){
    jd[d] = q2t[t*D_ + d];
    mk[d] = amask[t*D_ + d];
  }
  float acc[D_];
  #pragma unroll
  for (int d = 0; d < D_; ++d) acc[d] = 0.f;
  #pragma unroll 4
  for (int i = 0; i < CA_; ++i){
    float w = wp[i*CT_ + ct];
    #pragma unroll
    for (int d = 0; d < D_; ++d) acc[d] += qact[(size_t)jd[d]*CA_ + i] * w;
  }
  float num = 0.f, den = 1e-10f;
  #pragma unroll
  for (int d = 0; d < D_; ++d){
    num += mk[d] * fmaxf(acc[d], 0.f);
    den += mk[d];
  }
  out_tok[(size_t)t*CT_ + ct] = num/den;
}

extern "C" void kernel_launch(void* const* d_in, const int* in_sizes, int n_in,
                              void* d_out, int out_size, void* d_ws, size_t ws_size,
                              hipStream_t stream) {
  (void)in_sizes; (void)n_in; (void)out_size; (void)ws_size;
  const float* ref_positions = (const float*)d_in[0];
  const float* ref_mask      = (const float*)d_in[1];
  const float* ref_charge    = (const float*)d_in[2];
  const float* atom_mask     = (const float*)d_in[3];
  const int*   ref_element   = (const int*)d_in[4];
  const int*   ref_chars     = (const int*)d_in[5];
  const int*   ref_uid       = (const int*)d_in[6];
  const int*   t2q           = (const int*)d_in[7];
  const int*   q2k           = (const int*)d_in[8];
  const int*   q2t           = (const int*)d_in[9];
  const float* w_ref_pos     = (const float*)d_in[10];
  const float* w_ref_mask    = (const float*)d_in[11];
  const float* w_ref_element = (const float*)d_in[12];
  const float* w_ref_charge  = (const float*)d_in[13];
  const float* w_ref_name    = (const float*)d_in[14];
  const float* w_s2p_row1    = (const float*)d_in[15];
  const float* w_s2p_col1    = (const float*)d_in[16];
  const float* w_pair_off1   = (const float*)d_in[17];
  const float* w_pair_dist1  = (const float*)d_in[18];
  const float* w_pair_valid  = (const float*)d_in[19];
  const float* w_mlp1        = (const float*)d_in[20];
  const float* w_mlp2        = (const float*)d_in[21];
  const float* w_mlp3        = (const float*)d_in[22];
  const float* wq            = (const float*)d_in[23];
  const float* wk            = (const float*)d_in[24];
  const float* wv            = (const float*)d_in[25];
  const float* wb            = (const float*)d_in[26];
  const float* wo            = (const float*)d_in[27];
  const float* w_proj        = (const float*)d_in[28];

  char* ws = (char*)d_ws;
  float* qrp     = (float*)(ws + 9732096);
  int*   quid    = (int*)  (ws + 9953280);
  float* rowproj = (float*)(ws + 11206656);
  float* colproj = (float*)(ws + 12386304);
  float* Qp      = (float*)(ws + 13565952);
  float* Kp      = (float*)(ws + 23003136);
  float* Vp      = (float*)(ws + 32440320);
  float* O       = (float*)(ws + 41877504);
  u16*   biasws  = (u16*)  (ws + 60751872);

  float* out = (float*)d_out;
  float* out_tok   = out + 0;
  float* out_skip  = out + 294912;
  float* out_qmask = out + 2654208;
  float* out_qsc   = out + 2672640;
  float* out_kmask = out + 5031936;
  float* out_ksc   = out + 5105664;
  float* out_pair  = out + 14542848;

  hipLaunchKernelGGL(n_qsc, dim3(SQ_/8), dim3(128), 0, stream,
      ref_positions, ref_mask, ref_charge, atom_mask, ref_element, ref_chars, ref_uid, t2q,
      w_ref_pos, w_ref_mask, w_ref_element, w_ref_charge, w_ref_name,
      qrp, quid, out_qsc, out_qmask);
  hipLaunchKernelGGL(n_keys, dim3(SK_/16), dim3(128), 0, stream,
      out_qsc, out_qmask, q2k, out_ksc, out_kmask);
  hipLaunchKernelGGL(n_qkv, dim3(SQ_/16), dim3(128), 0, stream,
      out_qsc, wq, wk, wv, Qp, Kp, Vp);
  hipLaunchKernelGGL(n_proj16b, dim3(SQ_/4), dim3(128), 0, stream,
      out_qsc, w_s2p_row1, w_s2p_col1, rowproj, colproj);
  hipLaunchKernelGGL(n_pair, dim3(S_*4), dim3(128), 0, stream,
      q2k, rowproj, colproj, qrp, quid, ref_uid,
      w_mlp1, w_mlp2, w_mlp3, w_pair_off1, w_pair_dist1, w_pair_valid, wb,
      out_pair, biasws);
  hipLaunchKernelGGL(n_attn, dim3(S_*H_), dim3(64), 0, stream,
      Qp, Kp, Vp, out_kmask, biasws, q2k, O);
  hipLaunchKernelGGL(n_qact, dim3(SQ_/16), dim3(128), 0, stream,
      out_qsc, O, out_qmask, wo, out_skip);
  hipLaunchKernelGGL(n_tok, dim3(T_), dim3(384), 0, stream,
      out_skip, q2t, atom_mask, w_proj, out_tok);
}

// Round 12
// 508.518 us; speedup vs baseline: 1.2442x; 1.0133x over previous
//
#include <hip/hip_runtime.h>

typedef unsigned short u16;
typedef unsigned int u32;
typedef short bf16x8 __attribute__((ext_vector_type(8)));
typedef float f32x16 __attribute__((ext_vector_type(16)));

#define T_ 768
#define D_ 24
#define S_ 576
#define Q_ 32
#define K_ 128
#define CA_ 128
#define CP_ 16
#define CT_ 384
#define H_ 4
#define DH_ 32
#define SQ_ (S_*Q_)
#define SK_ (S_*K_)

__device__ __forceinline__ float b2f(u16 u){ return __uint_as_float(((u32)u)<<16); }
__device__ __forceinline__ u16 f2b(float f){ u32 x=__float_as_uint(f); return (u16)((x + 0x7fffu + ((x>>16)&1u))>>16); }

// Compiler-order fence for intra-wave LDS exchange (no runtime cost).
__device__ __forceinline__ void wave_fence(){
  __builtin_amdgcn_sched_barrier(0);
  __builtin_amdgcn_wave_barrier();
  __builtin_amdgcn_sched_barrier(0);
}

// ---- N1: per-atom conditioning gathered to query slots (8 slots/block) ----
__global__ __launch_bounds__(128) void n_qsc(
    const float* __restrict__ pos, const float* __restrict__ rmask, const float* __restrict__ charge,
    const float* __restrict__ amask, const int* __restrict__ elem, const int* __restrict__ chars,
    const int* __restrict__ uid, const int* __restrict__ t2q,
    const float* __restrict__ w_pos, const float* __restrict__ w_mask, const float* __restrict__ w_elem,
    const float* __restrict__ w_chg, const float* __restrict__ w_name,
    float* __restrict__ qrp, int* __restrict__ quid,
    float* __restrict__ out_qsc, float* __restrict__ out_qmask)
{
  int ch = threadIdx.x;
  #pragma unroll 1
  for (int sl = 0; sl < 8; ++sl){
    int slot = blockIdx.x*8 + sl;
    int a = t2q[slot];
    float p0 = pos[a*3+0], p1 = pos[a*3+1], p2 = pos[a*3+2];
    float m  = rmask[a];
    float cg = asinhf(charge[a]);
    int e  = elem[a];
    int c0 = chars[a*4+0], c1 = chars[a*4+1], c2 = chars[a*4+2], c3 = chars[a*4+3];
    float v = p0*w_pos[0*CA_+ch] + p1*w_pos[1*CA_+ch] + p2*w_pos[2*CA_+ch];
    v += m * w_mask[ch];
    v += w_elem[e*CA_+ch];
    v += cg * w_chg[ch];
    v += w_name[(0*64+c0)*CA_+ch] + w_name[(1*64+c1)*CA_+ch]
       + w_name[(2*64+c2)*CA_+ch] + w_name[(3*64+c3)*CA_+ch];
    v *= m;
    out_qsc[(size_t)slot*CA_+ch] = v;
    if (ch < 3) qrp[slot*3+ch] = pos[a*3+ch];
    if (ch == 0){
      out_qmask[slot] = amask[a];
      quid[slot] = uid[a];
    }
  }
}

// ---- N2 (merged): blocks [0,1152) = QKV projection + row/col proj16 for 16 rows;
//      blocks [1152,5760) = key-space gather copy (16 rows each).
//      All paths depend only on n_qsc outputs; mutually independent. ----
__global__ __launch_bounds__(128) void n_mid(
    const float* __restrict__ X, const float* __restrict__ qmask, const int* __restrict__ q2k,
    const float* __restrict__ wq, const float* __restrict__ wk, const float* __restrict__ wv,
    const float* __restrict__ Wr, const float* __restrict__ Wc,
    float* __restrict__ Qp, float* __restrict__ Kp, float* __restrict__ Vp,
    float* __restrict__ rowproj, float* __restrict__ colproj,
    float* __restrict__ out_ksc, float* __restrict__ out_kmask)
{
  int b = blockIdx.x;
  int tid = threadIdx.x;
  if (b < SQ_/16){
    // ---- QKV path ----
    int c = tid;
    size_t r0 = (size_t)b * 16;
    float aq[16], ak[16], av[16];
    #pragma unroll
    for (int r = 0; r < 16; ++r){ aq[r] = 0.f; ak[r] = 0.f; av[r] = 0.f; }
    #pragma unroll 4
    for (int i = 0; i < CA_; ++i){
      float q = wq[i*CA_+c];
      float k = wk[i*CA_+c];
      float v = wv[i*CA_+c];
      #pragma unroll
      for (int r = 0; r < 16; ++r){
        float x = X[(r0+r)*CA_ + i];
        aq[r] += x * q;
        ak[r] += x * k;
        av[r] += x * v;
      }
    }
    #pragma unroll
    for (int r = 0; r < 16; ++r){
      Qp[(r0+r)*CA_+c] = aq[r] * 0.17677669529663687f;
      Kp[(r0+r)*CA_+c] = ak[r];
      Vp[(r0+r)*CA_+c] = av[r];
    }
    // ---- proj16 append: 512 outputs (2 mats x 16 rows x 16 cols), 4 per thread ----
    #pragma unroll 1
    for (int rep = 0; rep < 4; ++rep){
      int idx = rep*128 + tid;
      int r = (idx >> 4) & 15;
      int cc = idx & 15;
      const float* W = (idx < 256) ? Wr : Wc;
      float* Y = (idx < 256) ? rowproj : colproj;
      float acc = 0.f;
      for (int i = 0; i < CA_; ++i)
        acc += fmaxf(X[(r0+r)*CA_+i], 0.f) * W[i*CP_+cc];
      Y[(r0+r)*CP_+cc] = acc;
    }
  } else {
    // ---- keys copy path ----
    int kb = b - SQ_/16;
    int e = tid & 31;
    int rr = tid >> 5;
    #pragma unroll
    for (int it = 0; it < 4; ++it){
      int sk = kb*16 + it*4 + rr;
      int j = q2k[sk];
      *(float4*)&out_ksc[(size_t)sk*CA_ + e*4] = *(const float4*)&X[(size_t)j*CA_ + e*4];
      if (e == 0) out_kmask[sk] = qmask[j];
    }
  }
}

// ---- N5: pair conditioning + MLP via bf16 MFMA (r9-verified) ----
__global__ __launch_bounds__(128) void n_pair(
    const int* __restrict__ q2k, const float* __restrict__ rowproj, const float* __restrict__ colproj,
    const float* __restrict__ qrp, const int* __restrict__ quid, const int* __restrict__ uid,
    const float* __restrict__ w1, const float* __restrict__ w2, const float* __restrict__ w3,
    const float* __restrict__ wpo, const float* __restrict__ wpd, const float* __restrict__ wpv,
    const float* __restrict__ wb,
    float* __restrict__ out_pair, u16* __restrict__ bias_ws)
{
  int tid = threadIdx.x;
  int w   = tid >> 6;
  int l   = tid & 63;
  int lo  = l & 31;
  int hi  = l >> 5;
  int ch0 = hi * 8;
  int s   = blockIdx.x >> 2;
  int qg  = blockIdx.x & 3;

  float wox[8], woy[8], woz[8], wdd[8], wvv[8];
  *(float4*)&wox[0] = *(const float4*)&wpo[ch0];      *(float4*)&wox[4] = *(const float4*)&wpo[ch0+4];
  *(float4*)&woy[0] = *(const float4*)&wpo[16+ch0];   *(float4*)&woy[4] = *(const float4*)&wpo[16+ch0+4];
  *(float4*)&woz[0] = *(const float4*)&wpo[32+ch0];   *(float4*)&woz[4] = *(const float4*)&wpo[32+ch0+4];
  *(float4*)&wdd[0] = *(const float4*)&wpd[ch0];      *(float4*)&wdd[4] = *(const float4*)&wpd[ch0+4];
  *(float4*)&wvv[0] = *(const float4*)&wpv[ch0];      *(float4*)&wvv[4] = *(const float4*)&wpv[ch0+4];

  bf16x8 A1, A2, A3;
  #pragma unroll
  for (int j = 0; j < 8; ++j){ A1[j] = 0; A2[j] = 0; A3[j] = 0; }
  if (lo < 16){
    #pragma unroll
    for (int j = 0; j < 8; ++j){
      A1[j] = (short)f2b(w1[(ch0+j)*16 + lo]);
      A2[j] = (short)f2b(w2[(ch0+j)*16 + lo]);
      A3[j] = (short)f2b(w3[(ch0+j)*16 + lo]);
    }
  }
  f32x16 Z;
  #pragma unroll
  for (int i = 0; i < 16; ++i) Z[i] = 0.f;

  #pragma unroll 1
  for (int q4 = 0; q4 < 4; ++q4){
    int q  = qg*8 + w*4 + q4;
    int sq = s*Q_ + q;
    float qx = qrp[sq*3+0], qy = qrp[sq*3+1], qz = qrp[sq*3+2];
    int   qu = quid[sq];
    float rp[8];
    *(float4*)&rp[0] = *(const float4*)&rowproj[(size_t)sq*CP_ + ch0];
    *(float4*)&rp[4] = *(const float4*)&rowproj[(size_t)sq*CP_ + ch0 + 4];

    #pragma unroll 1
    for (int kb = 0; kb < 4; ++kb){
      int k  = kb*32 + lo;
      int sk = s*K_ + k;
      int j  = q2k[sk];
      float kx = qrp[j*3+0], ky = qrp[j*3+1], kz = qrp[j*3+2];
      int   ku = uid[j];
      float cp[8];
      *(float4*)&cp[0] = *(const float4*)&colproj[(size_t)j*CP_ + ch0];
      *(float4*)&cp[4] = *(const float4*)&colproj[(size_t)j*CP_ + ch0 + 4];

      float ox = qx - kx, oy = qy - ky, oz = qz - kz;
      float vf = (qu == ku) ? 1.f : 0.f;
      float invd = vf / (1.f + ox*ox + oy*oy + oz*oz);

      float p[8];
      #pragma unroll
      for (int jj = 0; jj < 8; ++jj)
        p[jj] = rp[jj] + cp[jj]
              + vf*(ox*wox[jj] + oy*woy[jj] + oz*woz[jj])
              + invd*wdd[jj] + vf*wvv[jj];

      bf16x8 bfr;
      #pragma unroll
      for (int jj = 0; jj < 8; ++jj) bfr[jj] = (short)f2b(fmaxf(p[jj], 0.f));
      f32x16 d = __builtin_amdgcn_mfma_f32_32x32x16_bf16(A1, bfr, Z, 0, 0, 0);

      float t[8];
      #pragma unroll
      for (int r = 0; r < 8; ++r) t[r] = __shfl_xor(d[r], 32, 64);
      #pragma unroll
      for (int jj = 0; jj < 4; ++jj){
        float v0 = hi ? t[jj+4] : d[jj];
        float v1 = hi ? d[jj+4] : t[jj];
        bfr[jj]   = (short)f2b(fmaxf(v0, 0.f));
        bfr[jj+4] = (short)f2b(fmaxf(v1, 0.f));
      }
      d = __builtin_amdgcn_mfma_f32_32x32x16_bf16(A2, bfr, Z, 0, 0, 0);
      #pragma unroll
      for (int r = 0; r < 8; ++r) t[r] = __shfl_xor(d[r], 32, 64);
      #pragma unroll
      for (int jj = 0; jj < 4; ++jj){
        float v0 = hi ? t[jj+4] : d[jj];
        float v1 = hi ? d[jj+4] : t[jj];
        bfr[jj]   = (short)f2b(fmaxf(v0, 0.f));
        bfr[jj+4] = (short)f2b(fmaxf(v1, 0.f));
      }
      d = __builtin_amdgcn_mfma_f32_32x32x16_bf16(A3, bfr, Z, 0, 0, 0);
      #pragma unroll
      for (int r = 0; r < 8; ++r) t[r] = __shfl_xor(d[r], 32, 64);
      float pout[8];
      #pragma unroll
      for (int jj = 0; jj < 4; ++jj){
        pout[jj]   = p[jj]   + (hi ? t[jj+4] : d[jj]);
        pout[jj+4] = p[jj+4] + (hi ? d[jj+4] : t[jj]);
      }

      size_t ob = ((size_t)sq*K_ + k)*CP_ + ch0;
      *(float4*)&out_pair[ob]     = make_float4(pout[0], pout[1], pout[2], pout[3]);
      *(float4*)&out_pair[ob + 4] = make_float4(pout[4], pout[5], pout[6], pout[7]);

      float b0 = 0.f, b1 = 0.f, b2 = 0.f, b3 = 0.f;
      #pragma unroll
      for (int jj = 0; jj < 8; ++jj){
        float4 wv4 = *(const float4*)&wb[(ch0+jj)*4];
        float pj = pout[jj];
        b0 += pj*wv4.x; b1 += pj*wv4.y; b2 += pj*wv4.z; b3 += pj*wv4.w;
      }
      b0 += __shfl_xor(b0, 32, 64);
      b1 += __shfl_xor(b1, 32, 64);
      b2 += __shfl_xor(b2, 32, 64);
      b3 += __shfl_xor(b3, 32, 64);
      if (hi == 0){
        size_t bb = (((size_t)s*H_ + 0)*Q_ + q)*K_ + k;
        bias_ws[bb]             = f2b(b0);
        bias_ws[bb + Q_*K_]     = f2b(b1);
        bias_ws[bb + 2*Q_*K_]   = f2b(b2);
        bias_ws[bb + 3*Q_*K_]   = f2b(b3);
      }
    }
  }
}

// ---- N6: attention via bf16 MFMA. One 64-thread wave per (s,h). (r11-verified) ----
__global__ __launch_bounds__(64) void n_attn(
    const float* __restrict__ Qp, const float* __restrict__ Kp, const float* __restrict__ Vp,
    const float* __restrict__ kmask, const u16* __restrict__ bias_ws, const int* __restrict__ q2k,
    float* __restrict__ O)
{
  __shared__ float Ls[32*129];
  __shared__ float msk[K_];
  int t  = threadIdx.x;
  int lo = t & 31, hi = t >> 5;
  int b = blockIdx.x;
  int s = b >> 2, h = b & 3;
  int sq0 = s*Q_, base = s*K_;

  msk[t]      = kmask[base + t];
  msk[64 + t] = kmask[base + 64 + t];

  {
    const uint2* bsrc = (const uint2*)&bias_ws[(size_t)(s*H_ + h)*Q_*K_];
    #pragma unroll
    for (int i = 0; i < 16; ++i){
      int idx = i*64 + t;
      int q = idx >> 5, e = (idx & 31)*4;
      uint2 v = bsrc[idx];
      float* dst = &Ls[q*129 + e];
      dst[0] = b2f((u16)(v.x & 0xffffu));
      dst[1] = b2f((u16)(v.x >> 16));
      dst[2] = b2f((u16)(v.y & 0xffffu));
      dst[3] = b2f((u16)(v.y >> 16));
    }
  }

  bf16x8 Bq1, Bq2;
  {
    const float* qrow = &Qp[(size_t)(sq0+lo)*CA_ + h*DH_];
    float4 x0 = *(const float4*)&qrow[hi*8];
    float4 x1 = *(const float4*)&qrow[hi*8+4];
    float4 x2 = *(const float4*)&qrow[16+hi*8];
    float4 x3 = *(const float4*)&qrow[16+hi*8+4];
    Bq1[0]=(short)f2b(x0.x); Bq1[1]=(short)f2b(x0.y); Bq1[2]=(short)f2b(x0.z); Bq1[3]=(short)f2b(x0.w);
    Bq1[4]=(short)f2b(x1.x); Bq1[5]=(short)f2b(x1.y); Bq1[6]=(short)f2b(x1.z); Bq1[7]=(short)f2b(x1.w);
    Bq2[0]=(short)f2b(x2.x); Bq2[1]=(short)f2b(x2.y); Bq2[2]=(short)f2b(x2.z); Bq2[3]=(short)f2b(x2.w);
    Bq2[4]=(short)f2b(x3.x); Bq2[5]=(short)f2b(x3.y); Bq2[6]=(short)f2b(x3.z); Bq2[7]=(short)f2b(x3.w);
  }

  f32x16 Z;
  #pragma unroll
  for (int i = 0; i < 16; ++i) Z[i] = 0.f;

  f32x16 Sar[4];
  #pragma unroll
  for (int n = 0; n < 4; ++n){
    int jkn = q2k[base + 32*n + lo];
    const float* krow = &Kp[(size_t)jkn*CA_ + h*DH_];
    float4 x0 = *(const float4*)&krow[hi*8];
    float4 x1 = *(const float4*)&krow[hi*8+4];
    float4 x2 = *(const float4*)&krow[16+hi*8];
    float4 x3 = *(const float4*)&krow[16+hi*8+4];
    bf16x8 Ak1, Ak2;
    Ak1[0]=(short)f2b(x0.x); Ak1[1]=(short)f2b(x0.y); Ak1[2]=(short)f2b(x0.z); Ak1[3]=(short)f2b(x0.w);
    Ak1[4]=(short)f2b(x1.x); Ak1[5]=(short)f2b(x1.y); Ak1[6]=(short)f2b(x1.z); Ak1[7]=(short)f2b(x1.w);
    Ak2[0]=(short)f2b(x2.x); Ak2[1]=(short)f2b(x2.y); Ak2[2]=(short)f2b(x2.z); Ak2[3]=(short)f2b(x2.w);
    Ak2[4]=(short)f2b(x3.x); Ak2[5]=(short)f2b(x3.y); Ak2[6]=(short)f2b(x3.z); Ak2[7]=(short)f2b(x3.w);
    f32x16 d = __builtin_amdgcn_mfma_f32_32x32x16_bf16(Ak1, Bq1, Z, 0, 0, 0);
    Sar[n]   = __builtin_amdgcn_mfma_f32_32x32x16_bf16(Ak2, Bq2, d, 0, 0, 0);
  }

  wave_fence();

  float e_[4][16];
  float mx = -1e30f;
  #pragma unroll
  for (int n = 0; n < 4; ++n){
    #pragma unroll
    for (int r = 0; r < 16; ++r){
      int k = 32*n + (r&3) + 8*(r>>2) + 4*hi;
      float lg = (msk[k] > 0.f) ? (Sar[n][r] + Ls[lo*129 + k]) : -1e9f;
      e_[n][r] = lg;
      mx = fmaxf(mx, lg);
    }
  }
  mx = fmaxf(mx, __shfl_xor(mx, 32, 64));
  float sm = 0.f;
  #pragma unroll
  for (int n = 0; n < 4; ++n){
    #pragma unroll
    for (int r = 0; r < 16; ++r){
      float ee = __expf(e_[n][r] - mx);
      e_[n][r] = ee;
      sm += ee;
    }
  }
  sm += __shfl_xor(sm, 32, 64);
  float inv = 1.f / sm;

  f32x16 Dpv = Z;
  #pragma unroll
  for (int mt = 0; mt < 8; ++mt){
    bf16x8 Av;
    #pragma unroll
    for (int j = 0; j < 8; ++j){
      int kk = 16*mt + hi*8 + j;
      int jv = q2k[base + kk];
      Av[j] = (short)f2b(Vp[(size_t)jv*CA_ + h*DH_ + lo]);
    }
    bf16x8 Bp;
    int n  = mt >> 1;
    int m1 = mt & 1;
    #pragma unroll
    for (int j = 0; j < 4; ++j){
      int r0 = j + 8*m1;
      int r1 = r0 + 4;
      float o0 = e_[n][r0];
      float o1 = e_[n][r1];
      float x0 = __shfl_xor(o0, 32, 64);
      float x1 = __shfl_xor(o1, 32, 64);
      Bp[j]   = (short)f2b(hi ? x1 : o0);
      Bp[j+4] = (short)f2b(hi ? o1 : x0);
    }
    Dpv = __builtin_amdgcn_mfma_f32_32x32x16_bf16(Av, Bp, Dpv, 0, 0, 0);
  }

  wave_fence();
  #pragma unroll
  for (int b2 = 0; b2 < 4; ++b2){
    *(float4*)&Ls[lo*33 + 8*b2 + 4*hi] =
      make_float4(Dpv[4*b2+0]*inv, Dpv[4*b2+1]*inv, Dpv[4*b2+2]*inv, Dpv[4*b2+3]*inv);
  }
  wave_fence();
  #pragma unroll
  for (int it = 0; it < 4; ++it){
    int fid = it*64 + t;
    int qq = fid >> 3, e4 = fid & 7;
    float4 v = make_float4(Ls[qq*33 + e4*4 + 0], Ls[qq*33 + e4*4 + 1],
                           Ls[qq*33 + e4*4 + 2], Ls[qq*33 + e4*4 + 3]);
    *(float4*)&O[(size_t)(sq0+qq)*CA_ + h*DH_ + e4*4] = v;
  }
}

// ---- N7: queries_act = (qsc + O @ wo) * qmask -> out_skip only ----
__global__ __launch_bounds__(128) void n_qact(
    const float* __restrict__ qsc, const float* __restrict__ O, const float* __restrict__ qmask,
    const float* __restrict__ wo, float* __restrict__ out_skip)
{
  int c = threadIdx.x;
  size_t r0 = (size_t)blockIdx.x * 16;
  float acc[16];
  #pragma unroll
  for (int r = 0; r < 16; ++r) acc[r] = 0.f;
  #pragma unroll 4
  for (int i = 0; i < CA_; ++i){
    float w = wo[i*CA_+c];
    #pragma unroll
    for (int r = 0; r < 16; ++r) acc[r] += O[(r0+r)*CA_+i] * w;
  }
  #pragma unroll
  for (int r = 0; r < 16; ++r){
    float v = (qsc[(r0+r)*CA_+c] + acc[r]) * qmask[r0+r];
    out_skip[(r0+r)*CA_+c] = v;
  }
}

// ---- N8: proj + gather + masked mean ----
__global__ __launch_bounds__(384) void n_tok(
    const float* __restrict__ qact, const int* __restrict__ q2t, const float* __restrict__ amask,
    const float* __restrict__ wp, float* __restrict__ out_tok)
{
  int t = blockIdx.x, ct = threadIdx.x;
  int jd[D_];
  float mk[D_];
  #pragma unroll
  for (int d = 0; d < D_; ++d){
    jd[d] = q2t[t*D_ + d];
    mk[d] = amask[t*D_ + d];
  }
  float acc[D_];
  #pragma unroll
  for (int d = 0; d < D_; ++d) acc[d] = 0.f;
  #pragma unroll 4
  for (int i = 0; i < CA_; ++i){
    float w = wp[i*CT_ + ct];
    #pragma unroll
    for (int d = 0; d < D_; ++d) acc[d] += qact[(size_t)jd[d]*CA_ + i] * w;
  }
  float num = 0.f, den = 1e-10f;
  #pragma unroll
  for (int d = 0; d < D_; ++d){
    num += mk[d] * fmaxf(acc[d], 0.f);
    den += mk[d];
  }
  out_tok[(size_t)t*CT_ + ct] = num/den;
}

extern "C" void kernel_launch(void* const* d_in, const int* in_sizes, int n_in,
                              void* d_out, int out_size, void* d_ws, size_t ws_size,
                              hipStream_t stream) {
  (void)in_sizes; (void)n_in; (void)out_size; (void)ws_size;
  const float* ref_positions = (const float*)d_in[0];
  const float* ref_mask      = (const float*)d_in[1];
  const float* ref_charge    = (const float*)d_in[2];
  const float* atom_mask     = (const float*)d_in[3];
  const int*   ref_element   = (const int*)d_in[4];
  const int*   ref_chars     = (const int*)d_in[5];
  const int*   ref_uid       = (const int*)d_in[6];
  const int*   t2q           = (const int*)d_in[7];
  const int*   q2k           = (const int*)d_in[8];
  const int*   q2t           = (const int*)d_in[9];
  const float* w_ref_pos     = (const float*)d_in[10];
  const float* w_ref_mask    = (const float*)d_in[11];
  const float* w_ref_element = (const float*)d_in[12];
  const float* w_ref_charge  = (const float*)d_in[13];
  const float* w_ref_name    = (const float*)d_in[14];
  const float* w_s2p_row1    = (const float*)d_in[15];
  const float* w_s2p_col1    = (const float*)d_in[16];
  const float* w_pair_off1   = (const float*)d_in[17];
  const float* w_pair_dist1  = (const float*)d_in[18];
  const float* w_pair_valid  = (const float*)d_in[19];
  const float* w_mlp1        = (const float*)d_in[20];
  const float* w_mlp2        = (const float*)d_in[21];
  const float* w_mlp3        = (const float*)d_in[22];
  const float* wq            = (const float*)d_in[23];
  const float* wk            = (const float*)d_in[24];
  const float* wv            = (const float*)d_in[25];
  const float* wb            = (const float*)d_in[26];
  const float* wo            = (const float*)d_in[27];
  const float* w_proj        = (const float*)d_in[28];

  char* ws = (char*)d_ws;
  float* qrp     = (float*)(ws + 9732096);
  int*   quid    = (int*)  (ws + 9953280);
  float* rowproj = (float*)(ws + 11206656);
  float* colproj = (float*)(ws + 12386304);
  float* Qp      = (float*)(ws + 13565952);
  float* Kp      = (float*)(ws + 23003136);
  float* Vp      = (float*)(ws + 32440320);
  float* O       = (float*)(ws + 41877504);
  u16*   biasws  = (u16*)  (ws + 60751872);

  float* out = (float*)d_out;
  float* out_tok   = out + 0;
  float* out_skip  = out + 294912;
  float* out_qmask = out + 2654208;
  float* out_qsc   = out + 2672640;
  float* out_kmask = out + 5031936;
  float* out_ksc   = out + 5105664;
  float* out_pair  = out + 14542848;

  hipLaunchKernelGGL(n_qsc, dim3(SQ_/8), dim3(128), 0, stream,
      ref_positions, ref_mask, ref_charge, atom_mask, ref_element, ref_chars, ref_uid, t2q,
      w_ref_pos, w_ref_mask, w_ref_element, w_ref_charge, w_ref_name,
      qrp, quid, out_qsc, out_qmask);
  hipLaunchKernelGGL(n_mid, dim3(SQ_/16 + SK_/16), dim3(128), 0, stream,
      out_qsc, out_qmask, q2k, wq, wk, wv, w_s2p_row1, w_s2p_col1,
      Qp, Kp, Vp, rowproj, colproj, out_ksc, out_kmask);
  hipLaunchKernelGGL(n_pair, dim3(S_*4), dim3(128), 0, stream,
      q2k, rowproj, colproj, qrp, quid, ref_uid,
      w_mlp1, w_mlp2, w_mlp3, w_pair_off1, w_pair_dist1, w_pair_valid, wb,
      out_pair, biasws);
  hipLaunchKernelGGL(n_attn, dim3(S_*H_), dim3(64), 0, stream,
      Qp, Kp, Vp, out_kmask, biasws, q2k, O);
  hipLaunchKernelGGL(n_qact, dim3(SQ_/16), dim3(128), 0, stream,
      out_qsc, O, out_qmask, wo, out_skip);
  hipLaunchKernelGGL(n_tok, dim3(T_), dim3(384), 0, stream,
      out_skip, q2t, atom_mask, w_proj, out_tok);
}